// Round 3
// baseline (1323.809 us; speedup 1.0000x reference)
//
#include <hip/hip_runtime.h>

// ---------------------------------------------------------------------------
// PoseVQVAE fused forward. DUAL-MODE storage dtype (f32 vs bf16) sniffed
// on-device. Math core: bf16 MFMA 32x32x16, encoder 3-plane trunc-splits
// (split on READ from f32 LDS acts), decoder 1-plane.
// This round: BM=64 rows/block, 512 threads (8 waves x 32-col slices):
//  - each B short8 feeds 2 row-tiles (load:mfma ratio halved)
//  - fc1 A-loads ping-ponged 1 k-step ahead; fc2/3 B ping-ponged;
//    fc4/5/6/out preload whole B panel to registers (1 wait per layer)
//  - launch_bounds(512,4): VGPR cap 128 for prefetch headroom
// ---------------------------------------------------------------------------

using short8 = __attribute__((ext_vector_type(8))) short;
using f32x4  = __attribute__((ext_vector_type(4))) float;
using f32x16 = __attribute__((ext_vector_type(16))) float;

#define USHORT unsigned short
#define UINT   unsigned int

// plane sizes in ushorts
#define PS_W1  139264   // 544*256
#define PS_W2  65536    // 256*256
#define PS_MU  16384    // 256*64
#define PS_WE  65536    // 64*1024

// LDS geometry
#define STRF 260        // f32 activation stride (dword stride 260 -> 4-way max)
#define STRA 360        // dec sA stride (ushort; dword stride 180 -> 4-way max)
#define STRB 264        // dec sB stride (ushort)

// ---- ws layout (bytes), 64B-aligned ----
static const size_t OFF_COUNTS = 262144;    // 1024*4
static const size_t OFF_LOSS   = 266240;    // 4 (+pad)
static const size_t OFF_ENORM  = 266304;    // 1024*4
static const size_t OFF_W1     = 270400;    // 3 planes * 139264 * 2 = 835584
static const size_t OFF_W2     = 1105984;   // 3*65536*2 = 393216
static const size_t OFF_W3     = 1499200;   // 393216
static const size_t OFF_WMU    = 1892416;   // 3*16384*2 = 98304
static const size_t OFF_WE     = 1990720;   // 3*65536*2 = 393216
static const size_t OFF_W4     = 2383936;   // 352*256*2 = 180224
static const size_t OFF_W5     = 2564160;   // 131072
static const size_t OFF_W6     = 2695232;   // 131072
static const size_t OFF_WO     = 2826304;   // 256*288*2 = 147456 -> end ~2.98MB

__device__ __forceinline__ float b2f(USHORT u){
  return __uint_as_float(((UINT)u) << 16);
}
__device__ __forceinline__ USHORT f2b(float f){            // RNE f32->bf16
  UINT u = __float_as_uint(f);
  u += 0x7fffu + ((u >> 16) & 1u);
  return (USHORT)(u >> 16);
}
__device__ __forceinline__ float loadF(const void* p, long i, int f32m){
  if (f32m) return ((const float*)p)[i];
  return b2f(((const USHORT*)p)[i]);
}
// RNE 3-plane split (prep / weights)
__device__ __forceinline__ void split3(float h, USHORT& a, USHORT& b, USHORT& c){
  a = f2b(h); float r = h - b2f(a);
  b = f2b(r); r -= b2f(b);
  c = f2b(r);
}
// truncation 3-plane split (hot path): a+b+c == h to ~2^-24
__device__ __forceinline__ void splitT(float h, USHORT& a, USHORT& b, USHORT& c){
  UINT u = __float_as_uint(h);
  a = (USHORT)(u >> 16);
  float r = h - __uint_as_float(u & 0xffff0000u);
  UINT v = __float_as_uint(r);
  b = (USHORT)(v >> 16);
  float r2 = r - __uint_as_float(v & 0xffff0000u);
  c = f2b(r2);
}
__device__ __forceinline__ f32x4 mfma16(short8 a, short8 b, f32x4 c){
  return __builtin_amdgcn_mfma_f32_16x16x32_bf16(a, b, c, 0, 0, 0);
}
__device__ __forceinline__ f32x16 mfma32(short8 a, short8 b, f32x16 c){
  return __builtin_amdgcn_mfma_f32_32x32x16_bf16(a, b, c, 0, 0, 0);
}
__device__ __forceinline__ void zero16(f32x16& v){
  #pragma unroll
  for (int i = 0; i < 16; ++i) v[i] = 0.f;
}
// build 3 A-planes from 8 consecutive f32 in LDS (trunc split)
__device__ __forceinline__ void splitAT(const float* p, short8& A0, short8& A1, short8& A2){
  #pragma unroll
  for (int j = 0; j < 8; ++j){
    USHORT t0, t1, t2; splitT(p[j], t0, t1, t2);
    A0[j] = (short)t0; A1[j] = (short)t1; A2[j] = (short)t2;
  }
}
// dtype sniff (wave-uniform)
__device__ __forceinline__ int detect_f32(const void* x){
  UINT u = ((const UINT*)x)[threadIdx.x & 63];
  int e = (int)((u >> 7) & 0xFFu);
  unsigned long long m = __ballot(e >= 117 && e <= 130);
  return __popcll(m) < 32;
}

// ---------------------------------------------------------------------------
// prep: repack weights into [K/8][N][8] bf16 planes; enorm; zero accums.
// ---------------------------------------------------------------------------
__device__ __forceinline__ void fillW(USHORT* dst, const void* src,
                                      int Kpad, int N, int Ksrc, int Nsrc,
                                      int srcStride, bool kmajor, int t,
                                      int f32m, int planes)
{
  int total = Kpad * N;
  if (t >= total) return;
  int j = t & 7, rest = t >> 3;
  int n = rest % N, kg = rest / N;
  int k = kg*8 + j;
  float v = 0.f;
  if (k < Ksrc && n < Nsrc)
    v = loadF(src, kmajor ? (long)k*srcStride + n : (long)n*srcStride + k, f32m);
  if (planes == 1){ dst[t] = f2b(v); return; }
  USHORT t0, t1, t2; split3(v, t0, t1, t2);
  dst[t] = t0; dst[total + t] = t1; dst[2*total + t] = t2;
}

__global__ void vq_prep_kernel(
    const void* xx,
    const void* fc1w, const void* fc2w, const void* fc3w,
    const void* muw,  const void* fc4w, const void* fc5w,
    const void* fc6w, const void* outw, const void* embed,
    USHORT* W1p, USHORT* W2p, USHORT* W3p, USHORT* Wmup, USHORT* Wep,
    USHORT* W4p, USHORT* W5p, USHORT* W6p, USHORT* Wop,
    float* enorm, UINT* counts, float* loss_sum)
{
  int f32m = detect_f32(xx);
  int t = blockIdx.x * 256 + threadIdx.x;
  switch (blockIdx.y){
    case 0: fillW(W1p,  fc1w, 544, 256, 534, 256, 534, false, t, f32m, 3); break;
    case 1: fillW(W2p,  fc2w, 256, 256, 256, 256, 256, false, t, f32m, 3); break;
    case 2: fillW(W3p,  fc3w, 256, 256, 256, 256, 256, false, t, f32m, 3); break;
    case 3: fillW(Wmup, muw,  256,  64, 256,  64, 256, false, t, f32m, 3); break;
    case 4: fillW(Wep,  embed, 64, 1024, 64, 1024, 1024, true, t, f32m, 3); break;
    case 5: fillW(W4p,  fc4w, 352, 256, 331, 256, 331, false, t, f32m, 1); break;
    case 6: fillW(W5p,  fc5w, 256, 256, 256, 256, 256, false, t, f32m, 1); break;
    case 7: fillW(W6p,  fc6w, 256, 256, 256, 256, 256, false, t, f32m, 1); break;
    case 8: fillW(Wop,  outw, 256, 288, 256, 267, 256, false, t, f32m, 1); break;
    case 9:
      if (t < 1024){
        double s = 0.0;
        for (int l = 0; l < 64; ++l){
          double e = (double)loadF(embed, (long)l*1024 + t, f32m); s += e*e;
        }
        enorm[t] = (float)s;
      }
      break;
    case 10:
      if (t < 1024) counts[t] = 0u;
      if (t == 1024) *loss_sum = 0.f;
      break;
  }
}

// ---------------------------------------------------------------------------
// fused main: 64 rows/block, 512 threads (8 waves).
// Wave w owns ALL 64 rows x 32-col slice (tb0 = w*32).
// MFMA 32x32x16: A row = lane&31, k = (lane>>5)*8 + j;
//                C/D: col = lane&31, row = (reg&3) + 8*(reg>>2) + 4*(lane>>5)
// Two row-tiles per wave: R0 = rows 0-31 (acc0), R1 = rows 32-63 (acc1).
// ---------------------------------------------------------------------------
__global__ __launch_bounds__(512, 4) void vq_main_kernel(
    const void* __restrict__ x,  const void* __restrict__ cc,
    const void* __restrict__ b1, const void* __restrict__ b2,
    const void* __restrict__ b3, const void* __restrict__ bmu,
    const void* __restrict__ b4, const void* __restrict__ b5,
    const void* __restrict__ b6, const void* __restrict__ bo,
    const void* __restrict__ embed,
    const USHORT* __restrict__ W1p, const USHORT* __restrict__ W2p,
    const USHORT* __restrict__ W3p, const USHORT* __restrict__ Wmup,
    const USHORT* __restrict__ Wep, const float* __restrict__ enorm,
    const USHORT* __restrict__ W4p, const USHORT* __restrict__ W5p,
    const USHORT* __restrict__ W6p, const USHORT* __restrict__ Wop,
    UINT* __restrict__ counts, float* __restrict__ loss_sum,
    void* __restrict__ out)
{
  // union: enc f32 acts [64][260] (66560B)  ALIASED WITH
  //        dec sA [64][360] bf16 (46080B) + sB [64][264] bf16 (33792B) = 79872B
  // pMin/pCode (4KB) live at U+66560 (dead before sB is first written)
  __shared__ __align__(16) char U[79872];
  __shared__ int   codes[64];
  __shared__ float lossRed[8];
  float*  sF = (float*)U;                  // [64][STRF]
  USHORT* sA = (USHORT*)U;                 // [64][STRA]
  USHORT* sB = (USHORT*)(U + 46080);       // [64][STRB]
  float*  pMin  = (float*)(U + 66560);     // [8][64]
  int*    pCode = (int*)  (U + 68608);     // [8][64]

  const int f32m = detect_f32(x);
  const int tid  = threadIdx.x;
  const int w    = tid >> 6;
  const int lane = tid & 63;
  const int hi   = lane >> 5;
  const int nn   = lane & 31;
  const int quad = lane >> 4;
  const int l16  = lane & 15;
  const int tb0  = w * 32;                 // this wave's 32-col slice
  const long gbase = (long)blockIdx.x * 64;

  f32x16 acc0, acc1;                       // R0 / R1 row-tiles
  zero16(acc0); zero16(acc1);

  // ================= encoder =================
  // ---- fc1: K=544 (34 k-steps); A from global, software-pipelined
  if (f32m){
    float ca0[8], ca1[8], na0[8], na1[8];
    auto loadA8 = [&](int ks, float* a0, float* a1){
      #pragma unroll
      for (int j = 0; j < 8; ++j){
        int col = ks*16 + hi*8 + j;
        float v0 = 0.f, v1 = 0.f;
        if (col < 267){
          v0 = ((const float*)x)[(gbase + nn)*267 + col];
          v1 = ((const float*)x)[(gbase + nn + 32)*267 + col];
        } else if (col < 534){
          v0 = ((const float*)cc)[(gbase + nn)*267 + (col - 267)];
          v1 = ((const float*)cc)[(gbase + nn + 32)*267 + (col - 267)];
        }
        a0[j] = v0; a1[j] = v1;
      }
    };
    auto fc1body = [&](const float* a0, const float* a1, int ks){
      short8 A00, A01, A02, A10, A11, A12;
      #pragma unroll
      for (int j = 0; j < 8; ++j){
        USHORT t0, t1, t2;
        splitT(a0[j], t0, t1, t2); A00[j]=(short)t0; A01[j]=(short)t1; A02[j]=(short)t2;
        splitT(a1[j], t0, t1, t2); A10[j]=(short)t0; A11[j]=(short)t1; A12[j]=(short)t2;
      }
      const USHORT* bp = W1p + (((ks*2 + hi)*256) + tb0 + nn)*8;
      short8 B0 = *(const short8*)bp;
      short8 B1 = *(const short8*)(bp + PS_W1);
      short8 B2 = *(const short8*)(bp + 2*PS_W1);
      acc0 = mfma32(A00, B0, acc0); acc1 = mfma32(A10, B0, acc1);
      acc0 = mfma32(A01, B0, acc0); acc1 = mfma32(A11, B0, acc1);
      acc0 = mfma32(A02, B0, acc0); acc1 = mfma32(A12, B0, acc1);
      acc0 = mfma32(A00, B1, acc0); acc1 = mfma32(A10, B1, acc1);
      acc0 = mfma32(A01, B1, acc0); acc1 = mfma32(A11, B1, acc1);
      acc0 = mfma32(A00, B2, acc0); acc1 = mfma32(A10, B2, acc1);
    };
    loadA8(0, ca0, ca1);
    for (int ks = 0; ks < 34; ks += 2){
      loadA8(ks + 1, na0, na1);
      fc1body(ca0, ca1, ks);
      if (ks + 2 < 34) loadA8(ks + 2, ca0, ca1);
      fc1body(na0, na1, ks + 1);
    }
  } else {
    for (int ks = 0; ks < 34; ++ks){
      short8 A0a, A0b;
      #pragma unroll
      for (int j = 0; j < 8; ++j){
        int col = ks*16 + hi*8 + j;
        USHORT u0 = 0, u1 = 0;
        if (col < 267){
          u0 = ((const USHORT*)x)[(gbase + nn)*267 + col];
          u1 = ((const USHORT*)x)[(gbase + nn + 32)*267 + col];
        } else if (col < 534){
          u0 = ((const USHORT*)cc)[(gbase + nn)*267 + (col - 267)];
          u1 = ((const USHORT*)cc)[(gbase + nn + 32)*267 + (col - 267)];
        }
        A0a[j] = (short)u0; A0b[j] = (short)u1;
      }
      const USHORT* bp = W1p + (((ks*2 + hi)*256) + tb0 + nn)*8;
      short8 B0 = *(const short8*)bp;
      acc0 = mfma32(A0a, B0, acc0); acc1 = mfma32(A0b, B0, acc1);
    }
  }
  {
    float bs = loadF(b1, tb0 + nn, f32m);
    #pragma unroll
    for (int reg = 0; reg < 16; ++reg){
      int r = (reg&3) + 8*(reg>>2) + 4*hi;
      sF[(long)r*STRF + tb0 + nn]        = fmaxf(acc0[reg] + bs, 0.f);
      sF[(long)(r+32)*STRF + tb0 + nn]   = fmaxf(acc1[reg] + bs, 0.f);
    }
  }
  __syncthreads();

  // ---- fc2, fc3: in-place f32 LDS, trunc-split-on-read, K=256 (16 k-steps)
  for (int layer = 0; layer < 2; ++layer){
    const USHORT* Wp = layer ? W3p : W2p;
    const void*   bb = layer ? (const void*)b3 : (const void*)b2;
    zero16(acc0); zero16(acc1);
    short8 Bc0, Bc1, Bc2, Bn0, Bn1, Bn2;
    auto loadB3 = [&](int ks, short8& o0, short8& o1, short8& o2){
      const USHORT* bp = Wp + (((ks*2 + hi)*256) + tb0 + nn)*8;
      o0 = *(const short8*)bp;
      o1 = *(const short8*)(bp + PS_W2);
      o2 = *(const short8*)(bp + 2*PS_W2);
    };
    auto body = [&](int ks, short8 b0p, short8 b1p, short8 b2p){
      short8 A00, A01, A02, A10, A11, A12;
      splitAT(&sF[(long)nn*STRF + ks*16 + hi*8],        A00, A01, A02);
      splitAT(&sF[(long)(nn + 32)*STRF + ks*16 + hi*8], A10, A11, A12);
      acc0 = mfma32(A00, b0p, acc0); acc1 = mfma32(A10, b0p, acc1);
      acc0 = mfma32(A01, b0p, acc0); acc1 = mfma32(A11, b0p, acc1);
      acc0 = mfma32(A02, b0p, acc0); acc1 = mfma32(A12, b0p, acc1);
      if (f32m){
        acc0 = mfma32(A00, b1p, acc0); acc1 = mfma32(A10, b1p, acc1);
        acc0 = mfma32(A01, b1p, acc0); acc1 = mfma32(A11, b1p, acc1);
        acc0 = mfma32(A00, b2p, acc0); acc1 = mfma32(A10, b2p, acc1);
      }
    };
    loadB3(0, Bc0, Bc1, Bc2);
    for (int ks = 0; ks < 16; ks += 2){
      loadB3(ks + 1, Bn0, Bn1, Bn2);
      body(ks, Bc0, Bc1, Bc2);
      if (ks + 2 < 16) loadB3(ks + 2, Bc0, Bc1, Bc2);
      body(ks + 1, Bn0, Bn1, Bn2);
    }
    __syncthreads();
    {
      float bs = loadF(bb, tb0 + nn, f32m);
      #pragma unroll
      for (int reg = 0; reg < 16; ++reg){
        int r = (reg&3) + 8*(reg>>2) + 4*hi;
        sF[(long)r*STRF + tb0 + nn]      = fmaxf(acc0[reg] + bs, 0.f);
        sF[(long)(r+32)*STRF + tb0 + nn] = fmaxf(acc1[reg] + bs, 0.f);
      }
    }
    __syncthreads();
  }

  // ---- mu: N=64; wave w -> row-group rg = w>>2 (32 rows), cols (w&3)*16..+16
  {
    const int rg = w >> 2;
    const int mcol = (w & 3) * 16;
    f32x4 am0, am1;
    #pragma unroll
    for (int i = 0; i < 4; ++i){ am0[i] = 0.f; am1[i] = 0.f; }
    #pragma unroll 2
    for (int kc = 0; kc < 8; ++kc){
      short8 Aa0, Aa1, Aa2, Ab0, Ab1, Ab2;
      splitAT(&sF[(long)(rg*32 + l16)*STRF + kc*32 + quad*8],      Aa0, Aa1, Aa2);
      splitAT(&sF[(long)(rg*32 + 16 + l16)*STRF + kc*32 + quad*8], Ab0, Ab1, Ab2);
      const USHORT* bp = Wmup + ((kc*4 + quad)*64 + mcol + l16)*8;
      short8 Bm0 = *(const short8*)bp;
      am0 = mfma16(Aa0, Bm0, am0); am1 = mfma16(Ab0, Bm0, am1);
      am0 = mfma16(Aa1, Bm0, am0); am1 = mfma16(Ab1, Bm0, am1);
      am0 = mfma16(Aa2, Bm0, am0); am1 = mfma16(Ab2, Bm0, am1);
      if (f32m){
        short8 Bm1 = *(const short8*)(bp + PS_MU);
        am0 = mfma16(Aa0, Bm1, am0); am1 = mfma16(Ab0, Bm1, am1);
        am0 = mfma16(Aa1, Bm1, am0); am1 = mfma16(Ab1, Bm1, am1);
        short8 Bm2 = *(const short8*)(bp + 2*PS_MU);
        am0 = mfma16(Aa0, Bm2, am0); am1 = mfma16(Ab0, Bm2, am1);
      }
    }
    __syncthreads();
    float bm = loadF(bmu, mcol + l16, f32m);
    #pragma unroll
    for (int r = 0; r < 4; ++r){
      sF[(long)(rg*32 + quad*4 + r)*STRF + mcol + l16]      = am0[r] + bm;
      sF[(long)(rg*32 + 16 + quad*4 + r)*STRF + mcol + l16] = am1[r] + bm;
    }
    __syncthreads();
  }

  // ---- VQ: argmin_k(||e_k||^2 - 2 mu.e_k); wave w scans codes [w*128,+128)
  //      two row-tiles sequentially (rt = 0: rows 0-31, rt = 1: rows 32-63)
  for (int rt = 0; rt < 2; ++rt){
    short8 MA0[4], MA1[4], MA2[4];
    #pragma unroll
    for (int ks = 0; ks < 4; ++ks)
      splitAT(&sF[(long)(rt*32 + nn)*STRF + ks*16 + hi*8], MA0[ks], MA1[ks], MA2[ks]);
    float minv[16]; int minc[16];
    #pragma unroll
    for (int i = 0; i < 16; ++i){ minv[i] = 3.4e38f; minc[i] = 0; }
    #pragma unroll 1
    for (int tt = 0; tt < 4; ++tt){              // 32 codes per tile
      int cb = w*128 + tt*32;
      f32x16 ad; zero16(ad);
      #pragma unroll
      for (int ks = 0; ks < 4; ++ks){
        const USHORT* bp = Wep + (((ks*2 + hi)*1024) + cb + nn)*8;
        short8 B0 = *(const short8*)bp;
        ad = mfma32(MA0[ks], B0, ad);
        ad = mfma32(MA1[ks], B0, ad);
        ad = mfma32(MA2[ks], B0, ad);
        if (f32m){
          short8 B1 = *(const short8*)(bp + PS_WE);
          ad = mfma32(MA0[ks], B1, ad);
          ad = mfma32(MA1[ks], B1, ad);
          short8 B2 = *(const short8*)(bp + 2*PS_WE);
          ad = mfma32(MA0[ks], B2, ad);
        }
      }
      int code = cb + nn;
      float en = enorm[code];
      #pragma unroll
      for (int reg = 0; reg < 16; ++reg){
        float d = en - 2.f*ad[reg];
        if (d < minv[reg] || (d == minv[reg] && code < minc[reg])){ minv[reg] = d; minc[reg] = code; }
      }
    }
    // reduce across 32 code-lanes within each half (same hi => same rows)
    #pragma unroll
    for (int off = 16; off >= 1; off >>= 1){
      #pragma unroll
      for (int reg = 0; reg < 16; ++reg){
        float ov = __shfl_xor(minv[reg], off, 64);
        int   oc = __shfl_xor(minc[reg], off, 64);
        if (ov < minv[reg] || (ov == minv[reg] && oc < minc[reg])){ minv[reg] = ov; minc[reg] = oc; }
      }
    }
    if (nn == 0){
      #pragma unroll
      for (int reg = 0; reg < 16; ++reg){
        int r = (reg&3) + 8*(reg>>2) + 4*hi + rt*32;
        pMin[w*64 + r]  = minv[reg];
        pCode[w*64 + r] = minc[reg];
      }
    }
  }
  __syncthreads();

  // combine 8 wave-results per row (ascending ww -> lowest-index tie-break)
  if (tid < 64){
    float bv = pMin[tid]; int bc = pCode[tid];
    #pragma unroll
    for (int ww = 1; ww < 8; ++ww){
      float v = pMin[ww*64 + tid]; int cd = pCode[ww*64 + tid];
      if (v < bv || (v == bv && cd < bc)){ bv = v; bc = cd; }
    }
    codes[tid] = bc;
    atomicAdd(&counts[bc], 1u);
  }
  __syncthreads();

  // ---- loss: thread t -> (row = t>>3, dims (t&7)*8 ..+8)
  {
    int lrow = tid >> 3;
    int j0 = (tid & 7) * 8;
    int code = codes[lrow];
    float lp = 0.f;
    #pragma unroll
    for (int jj = 0; jj < 8; ++jj){
      int l = j0 + jj;
      float qv = loadF(embed, (long)l*1024 + code, f32m);
      float d = qv - sF[(long)lrow*STRF + l];
      lp += d*d;
    }
    #pragma unroll
    for (int off = 32; off >= 1; off >>= 1) lp += __shfl_xor(lp, off, 64);
    if (lane == 0) lossRed[w] = lp;
  }
  __syncthreads();                        // all sF reads done; sA may be written
  if (tid == 0){
    float s = 0.f;
    #pragma unroll
    for (int ww = 0; ww < 8; ++ww) s += lossRed[ww];
    atomicAdd(loss_sum, s);
  }

  // ================= decoder (bf16 1-plane) =================
  // stage s2 = [q | c | 0pad], width STRA (331 used)
  {
    int rr = tid >> 3, jg = tid & 7;      // q: 512 threads cover 64 rows x 8 groups
    int code = codes[rr];
    *(short8*)&sA[rr*STRA + jg*8] = *(const short8*)(Wep + ((long)jg*1024 + code)*8);
  }
  for (int rr = w*8; rr < w*8 + 8; ++rr){
    long grow = gbase + rr;
    for (int col = 64 + lane; col < STRA; col += 64){
      float v = (col < 331) ? loadF(cc, grow*267 + (col - 64), f32m) : 0.f;
      sA[rr*STRA + col] = f2b(v);
    }
  }
  __syncthreads();

  // ---- fc4: K=352 (22 k-steps, 2 chunks of 11 preloaded B) : sA -> sB
  zero16(acc0); zero16(acc1);
  #pragma unroll
  for (int ch = 0; ch < 2; ++ch){
    short8 Bk[11];
    #pragma unroll
    for (int i = 0; i < 11; ++i){
      int ks = ch*11 + i;
      Bk[i] = *(const short8*)(W4p + (((ks*2 + hi)*256) + tb0 + nn)*8);
    }
    #pragma unroll
    for (int i = 0; i < 11; ++i){
      int ks = ch*11 + i;
      short8 A0 = *(const short8*)&sA[nn*STRA + ks*16 + hi*8];
      short8 A1 = *(const short8*)&sA[(nn + 32)*STRA + ks*16 + hi*8];
      acc0 = mfma32(A0, Bk[i], acc0);
      acc1 = mfma32(A1, Bk[i], acc1);
    }
  }
  {
    float bs = loadF(b4, tb0 + nn, f32m);
    #pragma unroll
    for (int reg = 0; reg < 16; ++reg){
      int r = (reg&3) + 8*(reg>>2) + 4*hi;
      sB[r*STRB + tb0 + nn]        = f2b(fmaxf(acc0[reg] + bs, 0.f));
      sB[(r+32)*STRB + tb0 + nn]   = f2b(fmaxf(acc1[reg] + bs, 0.f));
    }
  }
  __syncthreads();

  // ---- fc5: sB -> sA (whole B panel preloaded)
  zero16(acc0); zero16(acc1);
  {
    short8 Bk[16];
    #pragma unroll
    for (int i = 0; i < 16; ++i)
      Bk[i] = *(const short8*)(W5p + (((i*2 + hi)*256) + tb0 + nn)*8);
    #pragma unroll
    for (int i = 0; i < 16; ++i){
      short8 A0 = *(const short8*)&sB[nn*STRB + i*16 + hi*8];
      short8 A1 = *(const short8*)&sB[(nn + 32)*STRB + i*16 + hi*8];
      acc0 = mfma32(A0, Bk[i], acc0);
      acc1 = mfma32(A1, Bk[i], acc1);
    }
  }
  __syncthreads();
  {
    float bs = loadF(b5, tb0 + nn, f32m);
    #pragma unroll
    for (int reg = 0; reg < 16; ++reg){
      int r = (reg&3) + 8*(reg>>2) + 4*hi;
      sA[r*STRA + tb0 + nn]        = f2b(fmaxf(acc0[reg] + bs, 0.f));
      sA[(r+32)*STRA + tb0 + nn]   = f2b(fmaxf(acc1[reg] + bs, 0.f));
    }
  }
  __syncthreads();

  // ---- fc6: sA -> sB
  zero16(acc0); zero16(acc1);
  {
    short8 Bk[16];
    #pragma unroll
    for (int i = 0; i < 16; ++i)
      Bk[i] = *(const short8*)(W6p + (((i*2 + hi)*256) + tb0 + nn)*8);
    #pragma unroll
    for (int i = 0; i < 16; ++i){
      short8 A0 = *(const short8*)&sA[nn*STRA + i*16 + hi*8];
      short8 A1 = *(const short8*)&sA[(nn + 32)*STRA + i*16 + hi*8];
      acc0 = mfma32(A0, Bk[i], acc0);
      acc1 = mfma32(A1, Bk[i], acc1);
    }
  }
  __syncthreads();
  {
    float bs = loadF(b6, tb0 + nn, f32m);
    #pragma unroll
    for (int reg = 0; reg < 16; ++reg){
      int r = (reg&3) + 8*(reg>>2) + 4*hi;
      sB[r*STRB + tb0 + nn]        = f2b(fmaxf(acc0[reg] + bs, 0.f));
      sB[(r+32)*STRB + tb0 + nn]   = f2b(fmaxf(acc1[reg] + bs, 0.f));
    }
  }
  __syncthreads();

  // ---- out: N=288 padded (267 real); wave w -> cols w*32..+31; w7 also 256..287
  {
    short8 Bk[16];
    #pragma unroll
    for (int i = 0; i < 16; ++i)
      Bk[i] = *(const short8*)(Wop + (((i*2 + hi)*288) + w*32 + nn)*8);
    f32x16 o0, o1; zero16(o0); zero16(o1);
    #pragma unroll
    for (int i = 0; i < 16; ++i){
      short8 A0 = *(const short8*)&sB[nn*STRB + i*16 + hi*8];
      short8 A1 = *(const short8*)&sB[(nn + 32)*STRB + i*16 + hi*8];
      o0 = mfma32(A0, Bk[i], o0);
      o1 = mfma32(A1, Bk[i], o1);
    }
    int col = w*32 + nn;                      // always < 256 -> real
    float bias = loadF(bo, col, f32m);
    #pragma unroll
    for (int reg = 0; reg < 16; ++reg){
      int r = (reg&3) + 8*(reg>>2) + 4*hi;
      long oi0 = (gbase + r)*267 + col;
      long oi1 = (gbase + r + 32)*267 + col;
      float v0 = o0[reg] + bias, v1 = o1[reg] + bias;
      if (f32m){ ((float*)out)[oi0] = v0; ((float*)out)[oi1] = v1; }
      else     { ((USHORT*)out)[oi0] = f2b(v0); ((USHORT*)out)[oi1] = f2b(v1); }
    }
  }
  if (w == 7){
    short8 Bk[16];
    #pragma unroll
    for (int i = 0; i < 16; ++i)
      Bk[i] = *(const short8*)(Wop + (((i*2 + hi)*288) + 256 + nn)*8);
    f32x16 o0, o1; zero16(o0); zero16(o1);
    #pragma unroll
    for (int i = 0; i < 16; ++i){
      short8 A0 = *(const short8*)&sB[nn*STRB + i*16 + hi*8];
      short8 A1 = *(const short8*)&sB[(nn + 32)*STRB + i*16 + hi*8];
      o0 = mfma32(A0, Bk[i], o0);
      o1 = mfma32(A1, Bk[i], o1);
    }
    int col = 256 + nn;
    if (col < 267){
      float bias = loadF(bo, col, f32m);
      #pragma unroll
      for (int reg = 0; reg < 16; ++reg){
        int r = (reg&3) + 8*(reg>>2) + 4*hi;
        long oi0 = (gbase + r)*267 + col;
        long oi1 = (gbase + r + 32)*267 + col;
        float v0 = o0[reg] + bias, v1 = o1[reg] + bias;
        if (f32m){ ((float*)out)[oi0] = v0; ((float*)out)[oi1] = v1; }
        else     { ((USHORT*)out)[oi0] = f2b(v0); ((USHORT*)out)[oi1] = f2b(v1); }
      }
    }
  }
}

// ---------------------------------------------------------------------------
// finalize: loss mean + perplexity from histogram
// ---------------------------------------------------------------------------
__global__ void vq_fin_kernel(const void* __restrict__ x,
                              const UINT* __restrict__ counts,
                              const float* __restrict__ loss_sum,
                              void* __restrict__ out)
{
  __shared__ float red[4];
  int f32m = detect_f32(x);
  int tid = threadIdx.x;
  float Hl = 0.f;
  for (int k = tid; k < 1024; k += 256){
    float p = (float)counts[k] * (1.f/65536.f);
    Hl -= p * logf(p + 1e-10f);
  }
  #pragma unroll
  for (int off = 32; off >= 1; off >>= 1) Hl += __shfl_xor(Hl, off, 64);
  if ((tid & 63) == 0) red[tid >> 6] = Hl;
  __syncthreads();
  if (tid == 0){
    float H = red[0] + red[1] + red[2] + red[3];
    float loss = *loss_sum * (1.f/4194304.f);   // /(B*L)
    float ppx  = expf(H);
    size_t base = (size_t)65536*267;
    if (f32m){
      ((float*)out)[base]     = loss;
      ((float*)out)[base + 1] = ppx;
    } else {
      ((USHORT*)out)[base]     = f2b(loss);
      ((USHORT*)out)[base + 1] = f2b(ppx);
    }
  }
}

// ---------------------------------------------------------------------------
extern "C" void kernel_launch(void* const* d_in, const int* in_sizes, int n_in,
                              void* d_out, int out_size, void* d_ws, size_t ws_size,
                              hipStream_t stream)
{
  const void* x    = d_in[0];
  const void* c    = d_in[1];
  const void* fc1w = d_in[2];
  const void* fc1b = d_in[3];
  const void* fc2w = d_in[4];
  const void* fc2b = d_in[5];
  const void* fc3w = d_in[6];
  const void* fc3b = d_in[7];
  const void* muw  = d_in[8];
  const void* mub  = d_in[9];
  const void* fc4w = d_in[10];
  const void* fc4b = d_in[11];
  const void* fc5w = d_in[12];
  const void* fc5b = d_in[13];
  const void* fc6w = d_in[14];
  const void* fc6b = d_in[15];
  const void* outw = d_in[16];
  const void* outb = d_in[17];
  const void* embed= d_in[18];

  char* ws = (char*)d_ws;
  UINT*   counts = (UINT*)  (ws + OFF_COUNTS);
  float*  lsum   = (float*) (ws + OFF_LOSS);
  float*  enorm  = (float*) (ws + OFF_ENORM);
  USHORT* W1p = (USHORT*)(ws + OFF_W1);
  USHORT* W2p = (USHORT*)(ws + OFF_W2);
  USHORT* W3p = (USHORT*)(ws + OFF_W3);
  USHORT* Wmup= (USHORT*)(ws + OFF_WMU);
  USHORT* Wep = (USHORT*)(ws + OFF_WE);
  USHORT* W4p = (USHORT*)(ws + OFF_W4);
  USHORT* W5p = (USHORT*)(ws + OFF_W5);
  USHORT* W6p = (USHORT*)(ws + OFF_W6);
  USHORT* Wop = (USHORT*)(ws + OFF_WO);

  dim3 pgrid(544, 11, 1);
  vq_prep_kernel<<<pgrid, 256, 0, stream>>>(
      x, fc1w, fc2w, fc3w, muw, fc4w, fc5w, fc6w, outw, embed,
      W1p, W2p, W3p, Wmup, Wep, W4p, W5p, W6p, Wop, enorm, counts, lsum);

  vq_main_kernel<<<1024, 512, 0, stream>>>(
      x, c, fc1b, fc2b, fc3b, mub, fc4b, fc5b, fc6b, outb, embed,
      W1p, W2p, W3p, Wmup, Wep, enorm,
      W4p, W5p, W6p, Wop, counts, lsum, d_out);

  vq_fin_kernel<<<1, 256, 0, stream>>>(x, counts, lsum, d_out);
}

// Round 4
// 1216.987 us; speedup vs baseline: 1.0878x; 1.0878x over previous
//
#include <hip/hip_runtime.h>

// ---------------------------------------------------------------------------
// PoseVQVAE fused forward. DUAL-MODE storage dtype (f32 vs bf16) sniffed
// on-device. Math core: bf16 MFMA 32x32x16 (main), 16x16x32 (mu).
// Encoder 3-plane trunc-splits; THIS ROUND: planes are computed ONCE on
// WRITE and stored as 3 bf16 LDS planes (sT0/1/2) -- readers ds_read_b128
// directly (no per-read split VALU, which was 4x-redundant across waves).
// Decoder 1-plane bf16, LDS-aliased. Structure otherwise = round-2 (1050us).
// ---------------------------------------------------------------------------

using short8 = __attribute__((ext_vector_type(8))) short;
using f32x4  = __attribute__((ext_vector_type(4))) float;
using f32x16 = __attribute__((ext_vector_type(16))) float;

#define USHORT unsigned short
#define UINT   unsigned int

// plane sizes in ushorts
#define PS_W1  139264   // 544*256
#define PS_W2  65536    // 256*256
#define PS_MU  16384    // 256*64
#define PS_WE  65536    // 64*1024

// LDS geometry
#define STRT 264        // act plane stride (ushort)
#define STRA 360        // dec sA stride (ushort)
#define STRB 264        // dec sB stride (ushort)

// ---- ws layout (bytes), 64B-aligned ----
static const size_t OFF_COUNTS = 262144;    // 1024*4
static const size_t OFF_LOSS   = 266240;    // 4 (+pad)
static const size_t OFF_ENORM  = 266304;    // 1024*4
static const size_t OFF_W1     = 270400;    // 3 planes * 139264 * 2 = 835584
static const size_t OFF_W2     = 1105984;   // 3*65536*2 = 393216
static const size_t OFF_W3     = 1499200;   // 393216
static const size_t OFF_WMU    = 1892416;   // 3*16384*2 = 98304
static const size_t OFF_WE     = 1990720;   // 3*65536*2 = 393216
static const size_t OFF_W4     = 2383936;   // 352*256*2 = 180224
static const size_t OFF_W5     = 2564160;   // 131072
static const size_t OFF_W6     = 2695232;   // 131072
static const size_t OFF_WO     = 2826304;   // 256*288*2 = 147456 -> end ~2.98MB

__device__ __forceinline__ float b2f(USHORT u){
  return __uint_as_float(((UINT)u) << 16);
}
__device__ __forceinline__ USHORT f2b(float f){            // RNE f32->bf16
  UINT u = __float_as_uint(f);
  u += 0x7fffu + ((u >> 16) & 1u);
  return (USHORT)(u >> 16);
}
__device__ __forceinline__ float loadF(const void* p, long i, int f32m){
  if (f32m) return ((const float*)p)[i];
  return b2f(((const USHORT*)p)[i]);
}
// RNE 3-plane split (prep / weights)
__device__ __forceinline__ void split3(float h, USHORT& a, USHORT& b, USHORT& c){
  a = f2b(h); float r = h - b2f(a);
  b = f2b(r); r -= b2f(b);
  c = f2b(r);
}
// truncation 3-plane split (hot path): a+b+c == h to ~2^-24
__device__ __forceinline__ void splitT(float h, USHORT& a, USHORT& b, USHORT& c){
  UINT u = __float_as_uint(h);
  a = (USHORT)(u >> 16);
  float r = h - __uint_as_float(u & 0xffff0000u);
  UINT v = __float_as_uint(r);
  b = (USHORT)(v >> 16);
  float r2 = r - __uint_as_float(v & 0xffff0000u);
  c = f2b(r2);
}
__device__ __forceinline__ f32x4 mfma16(short8 a, short8 b, f32x4 c){
  return __builtin_amdgcn_mfma_f32_16x16x32_bf16(a, b, c, 0, 0, 0);
}
__device__ __forceinline__ f32x16 mfma32(short8 a, short8 b, f32x16 c){
  return __builtin_amdgcn_mfma_f32_32x32x16_bf16(a, b, c, 0, 0, 0);
}
__device__ __forceinline__ void zero16(f32x16& v){
  #pragma unroll
  for (int i = 0; i < 16; ++i) v[i] = 0.f;
}
// dtype sniff (wave-uniform): bf16 storage -> low u16 exponent in [117,130]
__device__ __forceinline__ int detect_f32(const void* x){
  UINT u = ((const UINT*)x)[threadIdx.x & 63];
  int e = (int)((u >> 7) & 0xFFu);
  unsigned long long m = __ballot(e >= 117 && e <= 130);
  return __popcll(m) < 32;
}

// ---------------------------------------------------------------------------
// prep: repack weights into [K/8][N][8] bf16 planes; enorm; zero accums.
// ---------------------------------------------------------------------------
__device__ __forceinline__ void fillW(USHORT* dst, const void* src,
                                      int Kpad, int N, int Ksrc, int Nsrc,
                                      int srcStride, bool kmajor, int t,
                                      int f32m, int planes)
{
  int total = Kpad * N;
  if (t >= total) return;
  int j = t & 7, rest = t >> 3;
  int n = rest % N, kg = rest / N;
  int k = kg*8 + j;
  float v = 0.f;
  if (k < Ksrc && n < Nsrc)
    v = loadF(src, kmajor ? (long)k*srcStride + n : (long)n*srcStride + k, f32m);
  if (planes == 1){ dst[t] = f2b(v); return; }
  USHORT t0, t1, t2; split3(v, t0, t1, t2);
  dst[t] = t0; dst[total + t] = t1; dst[2*total + t] = t2;
}

__global__ void vq_prep_kernel(
    const void* xx,
    const void* fc1w, const void* fc2w, const void* fc3w,
    const void* muw,  const void* fc4w, const void* fc5w,
    const void* fc6w, const void* outw, const void* embed,
    USHORT* W1p, USHORT* W2p, USHORT* W3p, USHORT* Wmup, USHORT* Wep,
    USHORT* W4p, USHORT* W5p, USHORT* W6p, USHORT* Wop,
    float* enorm, UINT* counts, float* loss_sum)
{
  int f32m = detect_f32(xx);
  int t = blockIdx.x * 256 + threadIdx.x;
  switch (blockIdx.y){
    case 0: fillW(W1p,  fc1w, 544, 256, 534, 256, 534, false, t, f32m, 3); break;
    case 1: fillW(W2p,  fc2w, 256, 256, 256, 256, 256, false, t, f32m, 3); break;
    case 2: fillW(W3p,  fc3w, 256, 256, 256, 256, 256, false, t, f32m, 3); break;
    case 3: fillW(Wmup, muw,  256,  64, 256,  64, 256, false, t, f32m, 3); break;
    case 4: fillW(Wep,  embed, 64, 1024, 64, 1024, 1024, true, t, f32m, 3); break;
    case 5: fillW(W4p,  fc4w, 352, 256, 331, 256, 331, false, t, f32m, 1); break;
    case 6: fillW(W5p,  fc5w, 256, 256, 256, 256, 256, false, t, f32m, 1); break;
    case 7: fillW(W6p,  fc6w, 256, 256, 256, 256, 256, false, t, f32m, 1); break;
    case 8: fillW(Wop,  outw, 256, 288, 256, 267, 256, false, t, f32m, 1); break;
    case 9:
      if (t < 1024){
        double s = 0.0;
        for (int l = 0; l < 64; ++l){
          double e = (double)loadF(embed, (long)l*1024 + t, f32m); s += e*e;
        }
        enorm[t] = (float)s;
      }
      break;
    case 10:
      if (t < 1024) counts[t] = 0u;
      if (t == 1024) *loss_sum = 0.f;
      break;
  }
}

// ---------------------------------------------------------------------------
// fused main: 32 rows/block, 256 threads (4 waves).
// Wave w owns ALL 32 rows x 64-col slice (tb0 = w*64) -> B read once/block.
// MFMA 32x32x16: A row = lane&31, k = (lane>>5)*8 + j;
//                C/D: col = lane&31, row = (reg&3) + 8*(reg>>2) + 4*(lane>>5)
// Acts live as 3 bf16 planes sT0/1/2 [32][STRT]; split computed on write.
// ---------------------------------------------------------------------------
__global__ __launch_bounds__(256, 3) void vq_main_kernel(
    const void* __restrict__ x,  const void* __restrict__ cc,
    const void* __restrict__ b1, const void* __restrict__ b2,
    const void* __restrict__ b3, const void* __restrict__ bmu,
    const void* __restrict__ b4, const void* __restrict__ b5,
    const void* __restrict__ b6, const void* __restrict__ bo,
    const void* __restrict__ embed,
    const USHORT* __restrict__ W1p, const USHORT* __restrict__ W2p,
    const USHORT* __restrict__ W3p, const USHORT* __restrict__ Wmup,
    const USHORT* __restrict__ Wep, const float* __restrict__ enorm,
    const USHORT* __restrict__ W4p, const USHORT* __restrict__ W5p,
    const USHORT* __restrict__ W6p, const USHORT* __restrict__ Wop,
    UINT* __restrict__ counts, float* __restrict__ loss_sum,
    void* __restrict__ out)
{
  // union: enc planes sT0/1/2 [32][264] bf16 (3*16896 = 50688B) ALIASED WITH
  //        dec sA [32][360] bf16 (23040B) + sB [32][264] bf16 (16896B) = 39936B
  __shared__ __align__(16) char U[50688];
  __shared__ float rMin[4][32];
  __shared__ int   rCode[4][32];        // rCode[0] becomes codes[] after combine
  USHORT* sT0 = (USHORT*)U;                 // [32][STRT]
  USHORT* sT1 = (USHORT*)(U + 16896);
  USHORT* sT2 = (USHORT*)(U + 33792);
  USHORT* sA  = (USHORT*)U;                 // dec [32][STRA]
  USHORT* sB  = (USHORT*)(U + 23040);       // dec [32][STRB]

  const int f32m = detect_f32(x);
  const int tid  = threadIdx.x;
  const int w    = tid >> 6;
  const int lane = tid & 63;
  const int hi   = lane >> 5;
  const int nn   = lane & 31;
  const int quad = lane >> 4;
  const int l16  = lane & 15;
  const int tb0  = w * 64;                   // this wave's 64-col slice
  const long gbase = (long)blockIdx.x * 32;
  const long gr    = gbase + nn;             // global row for A fragments

  f32x16 acc0, acc1;
  zero16(acc0); zero16(acc1);

  // ================= encoder =================
  // ---- fc1: K=544 (34 k-steps of 16); A from global, trunc 3-plane split
  for (int ks = 0; ks < 34; ++ks){
    short8 A0, A1, A2;
    if (f32m){
      #pragma unroll
      for (int j = 0; j < 8; ++j){
        int col = ks*16 + hi*8 + j;
        float v = 0.f;
        if (col < 267)      v = ((const float*)x)[gr*267 + col];
        else if (col < 534) v = ((const float*)cc)[gr*267 + (col - 267)];
        USHORT t0, t1, t2; splitT(v, t0, t1, t2);
        A0[j] = (short)t0; A1[j] = (short)t1; A2[j] = (short)t2;
      }
    } else {
      #pragma unroll
      for (int j = 0; j < 8; ++j){
        int col = ks*16 + hi*8 + j;
        USHORT u = 0;
        if (col < 267)      u = ((const USHORT*)x)[gr*267 + col];
        else if (col < 534) u = ((const USHORT*)cc)[gr*267 + (col - 267)];
        A0[j] = (short)u;
      }
    }
    const USHORT* bp = W1p + (((ks*2 + hi)*256) + tb0 + nn)*8;
    short8 B00 = *(const short8*)bp;
    short8 B01 = *(const short8*)(bp + 256);
    if (!f32m){
      acc0 = mfma32(A0, B00, acc0); acc1 = mfma32(A0, B01, acc1);
    } else {
      short8 B10 = *(const short8*)(bp + PS_W1);
      short8 B11 = *(const short8*)(bp + PS_W1 + 256);
      short8 B20 = *(const short8*)(bp + 2*PS_W1);
      short8 B21 = *(const short8*)(bp + 2*PS_W1 + 256);
      acc0 = mfma32(A0, B00, acc0); acc1 = mfma32(A0, B01, acc1);
      acc0 = mfma32(A1, B00, acc0); acc1 = mfma32(A1, B01, acc1);
      acc0 = mfma32(A2, B00, acc0); acc1 = mfma32(A2, B01, acc1);
      acc0 = mfma32(A0, B10, acc0); acc1 = mfma32(A0, B11, acc1);
      acc0 = mfma32(A1, B10, acc0); acc1 = mfma32(A1, B11, acc1);
      acc0 = mfma32(A0, B20, acc0); acc1 = mfma32(A0, B21, acc1);
    }
  }
  {
    float bs0 = loadF(b1, tb0 + nn, f32m);
    float bs1 = loadF(b1, tb0 + 32 + nn, f32m);
    #pragma unroll
    for (int reg = 0; reg < 16; ++reg){
      int r = (reg&3) + 8*(reg>>2) + 4*hi;
      float h0 = fmaxf(acc0[reg] + bs0, 0.f);
      float h1 = fmaxf(acc1[reg] + bs1, 0.f);
      USHORT t0,t1,t2;
      splitT(h0, t0,t1,t2);
      sT0[r*STRT + tb0 + nn] = t0; sT1[r*STRT + tb0 + nn] = t1; sT2[r*STRT + tb0 + nn] = t2;
      splitT(h1, t0,t1,t2);
      sT0[r*STRT + tb0 + 32 + nn] = t0; sT1[r*STRT + tb0 + 32 + nn] = t1; sT2[r*STRT + tb0 + 32 + nn] = t2;
    }
  }
  __syncthreads();

  // ---- fc2, fc3: in-place plane LDS, ds_read planes, K=256 (16 k-steps)
  for (int layer = 0; layer < 2; ++layer){
    const USHORT* Wp = layer ? W3p : W2p;
    const void*   bb = layer ? (const void*)b3 : (const void*)b2;
    zero16(acc0); zero16(acc1);
    #pragma unroll 2
    for (int ks = 0; ks < 16; ++ks){
      const int ao = nn*STRT + ks*16 + hi*8;
      short8 A0 = *(const short8*)&sT0[ao];
      short8 A1 = *(const short8*)&sT1[ao];
      short8 A2 = *(const short8*)&sT2[ao];
      const USHORT* bp = Wp + (((ks*2 + hi)*256) + tb0 + nn)*8;
      short8 B00 = *(const short8*)bp;
      short8 B01 = *(const short8*)(bp + 256);
      acc0 = mfma32(A0, B00, acc0); acc1 = mfma32(A0, B01, acc1);
      acc0 = mfma32(A1, B00, acc0); acc1 = mfma32(A1, B01, acc1);
      acc0 = mfma32(A2, B00, acc0); acc1 = mfma32(A2, B01, acc1);
      if (f32m){
        short8 B10 = *(const short8*)(bp + PS_W2);
        short8 B11 = *(const short8*)(bp + PS_W2 + 256);
        short8 B20 = *(const short8*)(bp + 2*PS_W2);
        short8 B21 = *(const short8*)(bp + 2*PS_W2 + 256);
        acc0 = mfma32(A0, B10, acc0); acc1 = mfma32(A0, B11, acc1);
        acc0 = mfma32(A1, B10, acc0); acc1 = mfma32(A1, B11, acc1);
        acc0 = mfma32(A0, B20, acc0); acc1 = mfma32(A0, B21, acc1);
      }
    }
    __syncthreads();
    {
      float bs0 = loadF(bb, tb0 + nn, f32m);
      float bs1 = loadF(bb, tb0 + 32 + nn, f32m);
      #pragma unroll
      for (int reg = 0; reg < 16; ++reg){
        int r = (reg&3) + 8*(reg>>2) + 4*hi;
        float h0 = fmaxf(acc0[reg] + bs0, 0.f);
        float h1 = fmaxf(acc1[reg] + bs1, 0.f);
        USHORT t0,t1,t2;
        splitT(h0, t0,t1,t2);
        sT0[r*STRT + tb0 + nn] = t0; sT1[r*STRT + tb0 + nn] = t1; sT2[r*STRT + tb0 + nn] = t2;
        splitT(h1, t0,t1,t2);
        sT0[r*STRT + tb0 + 32 + nn] = t0; sT1[r*STRT + tb0 + 32 + nn] = t1; sT2[r*STRT + tb0 + 32 + nn] = t2;
      }
    }
    __syncthreads();
  }

  // ---- mu: N=64, 16x16x32 (wave w -> 16-col tile), dual row-groups, no relu
  {
    f32x4 am0, am1;
    #pragma unroll
    for (int i = 0; i < 4; ++i){ am0[i] = 0.f; am1[i] = 0.f; }
    #pragma unroll 2
    for (int kc = 0; kc < 8; ++kc){
      const int aoa = l16*STRT + kc*32 + quad*8;
      const int aob = (l16 + 16)*STRT + kc*32 + quad*8;
      short8 Aa0 = *(const short8*)&sT0[aoa];
      short8 Aa1 = *(const short8*)&sT1[aoa];
      short8 Aa2 = *(const short8*)&sT2[aoa];
      short8 Ab0 = *(const short8*)&sT0[aob];
      short8 Ab1 = *(const short8*)&sT1[aob];
      short8 Ab2 = *(const short8*)&sT2[aob];
      const USHORT* bp = Wmup + ((kc*4 + quad)*64 + w*16 + l16)*8;
      short8 Bm0 = *(const short8*)bp;
      am0 = mfma16(Aa0, Bm0, am0); am1 = mfma16(Ab0, Bm0, am1);
      am0 = mfma16(Aa1, Bm0, am0); am1 = mfma16(Ab1, Bm0, am1);
      am0 = mfma16(Aa2, Bm0, am0); am1 = mfma16(Ab2, Bm0, am1);
      if (f32m){
        short8 Bm1 = *(const short8*)(bp + PS_MU);
        am0 = mfma16(Aa0, Bm1, am0); am1 = mfma16(Ab0, Bm1, am1);
        am0 = mfma16(Aa1, Bm1, am0); am1 = mfma16(Ab1, Bm1, am1);
        short8 Bm2 = *(const short8*)(bp + 2*PS_MU);
        am0 = mfma16(Aa0, Bm2, am0); am1 = mfma16(Ab0, Bm2, am1);
      }
    }
    __syncthreads();
    float bm = loadF(bmu, w*16 + l16, f32m);
    #pragma unroll
    for (int r = 0; r < 4; ++r){
      float m0 = am0[r] + bm;
      float m1 = am1[r] + bm;
      USHORT t0,t1,t2;
      splitT(m0, t0,t1,t2);
      sT0[(quad*4 + r)*STRT + w*16 + l16] = t0;
      sT1[(quad*4 + r)*STRT + w*16 + l16] = t1;
      sT2[(quad*4 + r)*STRT + w*16 + l16] = t2;
      splitT(m1, t0,t1,t2);
      sT0[(quad*4 + r + 16)*STRT + w*16 + l16] = t0;
      sT1[(quad*4 + r + 16)*STRT + w*16 + l16] = t1;
      sT2[(quad*4 + r + 16)*STRT + w*16 + l16] = t2;
    }
    __syncthreads();
  }

  // ---- VQ: argmin_k(||e_k||^2 - 2 mu.e_k); wave w scans codes [w*256, +256)
  {
    short8 MA0[4], MA1[4], MA2[4];
    #pragma unroll
    for (int ks = 0; ks < 4; ++ks){
      const int ao = nn*STRT + ks*16 + hi*8;
      MA0[ks] = *(const short8*)&sT0[ao];
      MA1[ks] = *(const short8*)&sT1[ao];
      MA2[ks] = *(const short8*)&sT2[ao];
    }
    float minv[16]; int minc[16];
    #pragma unroll
    for (int i = 0; i < 16; ++i){ minv[i] = 3.4e38f; minc[i] = 0; }
    for (int tt = 0; tt < 8; ++tt){              // 32 codes per tile
      int cb = w*256 + tt*32;
      f32x16 ad; zero16(ad);
      #pragma unroll
      for (int ks = 0; ks < 4; ++ks){
        const USHORT* bp = Wep + (((ks*2 + hi)*1024) + cb + nn)*8;
        short8 B0 = *(const short8*)bp;
        ad = mfma32(MA0[ks], B0, ad);
        ad = mfma32(MA1[ks], B0, ad);
        ad = mfma32(MA2[ks], B0, ad);
        if (f32m){
          short8 B1 = *(const short8*)(bp + PS_WE);
          ad = mfma32(MA0[ks], B1, ad);
          ad = mfma32(MA1[ks], B1, ad);
          short8 B2 = *(const short8*)(bp + 2*PS_WE);
          ad = mfma32(MA0[ks], B2, ad);
        }
      }
      int code = cb + nn;
      float en = enorm[code];
      #pragma unroll
      for (int reg = 0; reg < 16; ++reg){
        float d = en - 2.f*ad[reg];
        if (d < minv[reg] || (d == minv[reg] && code < minc[reg])){ minv[reg] = d; minc[reg] = code; }
      }
    }
    // reduce across the 32 code-lanes of each half (rows differ by half!)
    #pragma unroll
    for (int off = 16; off >= 1; off >>= 1){
      #pragma unroll
      for (int reg = 0; reg < 16; ++reg){
        float ov = __shfl_xor(minv[reg], off, 64);
        int   oc = __shfl_xor(minc[reg], off, 64);
        if (ov < minv[reg] || (ov == minv[reg] && oc < minc[reg])){ minv[reg] = ov; minc[reg] = oc; }
      }
    }
    if (nn == 0){
      #pragma unroll
      for (int reg = 0; reg < 16; ++reg){
        int r = (reg&3) + 8*(reg>>2) + 4*hi;
        rMin[w][r]  = minv[reg];
        rCode[w][r] = minc[reg];
      }
    }
  }
  __syncthreads();

  // combine the 4 wave-quarters (ascending -> lowest-index tie-break), histogram
  if (tid < 32){
    float bv = rMin[0][tid]; int bc = rCode[0][tid];
    #pragma unroll
    for (int ww = 1; ww < 4; ++ww){
      float v = rMin[ww][tid]; int cd = rCode[ww][tid];
      if (v < bv || (v == bv && cd < bc)){ bv = v; bc = cd; }
    }
    rCode[0][tid] = bc;                      // codes[]
    atomicAdd(&counts[bc], 1u);
  }
  __syncthreads();

  // ---- loss: thread t -> (row = t>>3, dims (t&7)*8 ..+8); mu = sum of planes
  {
    int lrow = tid >> 3;
    int j0 = (tid & 7) * 8;
    int code = rCode[0][lrow];
    float lp = 0.f;
    #pragma unroll
    for (int jj = 0; jj < 8; ++jj){
      int l = j0 + jj;
      float qv = loadF(embed, (long)l*1024 + code, f32m);
      float muf = b2f(sT0[lrow*STRT + l]) + b2f(sT1[lrow*STRT + l]) + b2f(sT2[lrow*STRT + l]);
      float d = qv - muf;
      lp += d*d;
    }
    #pragma unroll
    for (int off = 32; off >= 1; off >>= 1) lp += __shfl_xor(lp, off, 64);
    if (lane == 0) rMin[0][w] = lp;
  }
  __syncthreads();                            // all sT reads done; sA may be written
  if (tid == 0)
    atomicAdd(loss_sum, rMin[0][0] + rMin[0][1] + rMin[0][2] + rMin[0][3]);

  // ================= decoder (bf16 1-plane) =================
  // stage s2 = [q | c | 0pad], width 360 (331 used)
  {
    // q: from Wep plane0 ( == f2b(embed) ), 8 contiguous short8 per row
    int rr = tid >> 3, jg = tid & 7;
    int code = rCode[0][rr];
    short8 qv = *(const short8*)(Wep + ((long)jg*1024 + code)*8);
    *(short8*)&sA[rr*STRA + jg*8] = qv;
  }
  for (int rr = w*8; rr < w*8 + 8; ++rr){
    long grow = gbase + rr;
    for (int col = 64 + lane; col < 360; col += 64){
      float v = (col < 331) ? loadF(cc, grow*267 + (col - 64), f32m) : 0.f;
      sA[rr*STRA + col] = f2b(v);
    }
  }
  __syncthreads();

  // ---- fc4: K=352 (22 k-steps) : sA -> sB
  zero16(acc0); zero16(acc1);
  #pragma unroll 2
  for (int ks = 0; ks < 22; ++ks){
    short8 A = *(const short8*)&sA[nn*STRA + ks*16 + hi*8];
    const USHORT* bp = W4p + (((ks*2 + hi)*256) + tb0 + nn)*8;
    acc0 = mfma32(A, *(const short8*)bp,         acc0);
    acc1 = mfma32(A, *(const short8*)(bp + 256), acc1);
  }
  {
    float bs0 = loadF(b4, tb0 + nn, f32m);
    float bs1 = loadF(b4, tb0 + 32 + nn, f32m);
    #pragma unroll
    for (int reg = 0; reg < 16; ++reg){
      int r = (reg&3) + 8*(reg>>2) + 4*hi;
      sB[r*STRB + tb0 + nn]      = f2b(fmaxf(acc0[reg] + bs0, 0.f));
      sB[r*STRB + tb0 + 32 + nn] = f2b(fmaxf(acc1[reg] + bs1, 0.f));
    }
  }
  __syncthreads();

  // ---- fc5: sB -> sA (in-place-flip: barrier between read and write)
  zero16(acc0); zero16(acc1);
  #pragma unroll 4
  for (int ks = 0; ks < 16; ++ks){
    short8 A = *(const short8*)&sB[nn*STRB + ks*16 + hi*8];
    const USHORT* bp = W5p + (((ks*2 + hi)*256) + tb0 + nn)*8;
    acc0 = mfma32(A, *(const short8*)bp,         acc0);
    acc1 = mfma32(A, *(const short8*)(bp + 256), acc1);
  }
  __syncthreads();
  {
    float bs0 = loadF(b5, tb0 + nn, f32m);
    float bs1 = loadF(b5, tb0 + 32 + nn, f32m);
    #pragma unroll
    for (int reg = 0; reg < 16; ++reg){
      int r = (reg&3) + 8*(reg>>2) + 4*hi;
      sA[r*STRA + tb0 + nn]      = f2b(fmaxf(acc0[reg] + bs0, 0.f));
      sA[r*STRA + tb0 + 32 + nn] = f2b(fmaxf(acc1[reg] + bs1, 0.f));
    }
  }
  __syncthreads();

  // ---- fc6: sA -> sB
  zero16(acc0); zero16(acc1);
  #pragma unroll 4
  for (int ks = 0; ks < 16; ++ks){
    short8 A = *(const short8*)&sA[nn*STRA + ks*16 + hi*8];
    const USHORT* bp = W6p + (((ks*2 + hi)*256) + tb0 + nn)*8;
    acc0 = mfma32(A, *(const short8*)bp,         acc0);
    acc1 = mfma32(A, *(const short8*)(bp + 256), acc1);
  }
  __syncthreads();
  {
    float bs0 = loadF(b6, tb0 + nn, f32m);
    float bs1 = loadF(b6, tb0 + 32 + nn, f32m);
    #pragma unroll
    for (int reg = 0; reg < 16; ++reg){
      int r = (reg&3) + 8*(reg>>2) + 4*hi;
      sB[r*STRB + tb0 + nn]      = f2b(fmaxf(acc0[reg] + bs0, 0.f));
      sB[r*STRB + tb0 + 32 + nn] = f2b(fmaxf(acc1[reg] + bs1, 0.f));
    }
  }
  __syncthreads();

  // ---- out: N=288 padded (267 real); waves 0-2: 2 tiles, wave 3: 3 tiles
  {
    f32x16 acco0, acco1, acco2;
    zero16(acco0); zero16(acco1); zero16(acco2);
    #pragma unroll 2
    for (int ks = 0; ks < 16; ++ks){
      short8 A = *(const short8*)&sB[nn*STRB + ks*16 + hi*8];
      const USHORT* bp = Wop + (((ks*2 + hi)*288) + w*64 + nn)*8;
      acco0 = mfma32(A, *(const short8*)bp,         acco0);
      acco1 = mfma32(A, *(const short8*)(bp + 256), acco1);
      if (w == 3) acco2 = mfma32(A, *(const short8*)(bp + 512), acco2);
    }
    int ntiles = (w == 3) ? 3 : 2;
    #pragma unroll
    for (int t = 0; t < 3; ++t){
      if (t < ntiles){
        int col = w*64 + t*32 + nn;
        if (col < 267){
          float bias = loadF(bo, col, f32m);
          f32x16& a = (t == 0) ? acco0 : (t == 1) ? acco1 : acco2;
          #pragma unroll
          for (int reg = 0; reg < 16; ++reg){
            int r = (reg&3) + 8*(reg>>2) + 4*hi;
            long oi = (gbase + r)*267 + col;
            float val = a[reg] + bias;
            if (f32m) ((float*)out)[oi] = val;
            else      ((USHORT*)out)[oi] = f2b(val);
          }
        }
      }
    }
  }
}

// ---------------------------------------------------------------------------
// finalize: loss mean + perplexity from histogram
// ---------------------------------------------------------------------------
__global__ void vq_fin_kernel(const void* __restrict__ x,
                              const UINT* __restrict__ counts,
                              const float* __restrict__ loss_sum,
                              void* __restrict__ out)
{
  __shared__ float red[4];
  int f32m = detect_f32(x);
  int tid = threadIdx.x;
  float Hl = 0.f;
  for (int k = tid; k < 1024; k += 256){
    float p = (float)counts[k] * (1.f/65536.f);
    Hl -= p * logf(p + 1e-10f);
  }
  #pragma unroll
  for (int off = 32; off >= 1; off >>= 1) Hl += __shfl_xor(Hl, off, 64);
  if ((tid & 63) == 0) red[tid >> 6] = Hl;
  __syncthreads();
  if (tid == 0){
    float H = red[0] + red[1] + red[2] + red[3];
    float loss = *loss_sum * (1.f/4194304.f);   // /(B*L)
    float ppx  = expf(H);
    size_t base = (size_t)65536*267;
    if (f32m){
      ((float*)out)[base]     = loss;
      ((float*)out)[base + 1] = ppx;
    } else {
      ((USHORT*)out)[base]     = f2b(loss);
      ((USHORT*)out)[base + 1] = f2b(ppx);
    }
  }
}

// ---------------------------------------------------------------------------
extern "C" void kernel_launch(void* const* d_in, const int* in_sizes, int n_in,
                              void* d_out, int out_size, void* d_ws, size_t ws_size,
                              hipStream_t stream)
{
  const void* x    = d_in[0];
  const void* c    = d_in[1];
  const void* fc1w = d_in[2];
  const void* fc1b = d_in[3];
  const void* fc2w = d_in[4];
  const void* fc2b = d_in[5];
  const void* fc3w = d_in[6];
  const void* fc3b = d_in[7];
  const void* muw  = d_in[8];
  const void* mub  = d_in[9];
  const void* fc4w = d_in[10];
  const void* fc4b = d_in[11];
  const void* fc5w = d_in[12];
  const void* fc5b = d_in[13];
  const void* fc6w = d_in[14];
  const void* fc6b = d_in[15];
  const void* outw = d_in[16];
  const void* outb = d_in[17];
  const void* embed= d_in[18];

  char* ws = (char*)d_ws;
  UINT*   counts = (UINT*)  (ws + OFF_COUNTS);
  float*  lsum   = (float*) (ws + OFF_LOSS);
  float*  enorm  = (float*) (ws + OFF_ENORM);
  USHORT* W1p = (USHORT*)(ws + OFF_W1);
  USHORT* W2p = (USHORT*)(ws + OFF_W2);
  USHORT* W3p = (USHORT*)(ws + OFF_W3);
  USHORT* Wmup= (USHORT*)(ws + OFF_WMU);
  USHORT* Wep = (USHORT*)(ws + OFF_WE);
  USHORT* W4p = (USHORT*)(ws + OFF_W4);
  USHORT* W5p = (USHORT*)(ws + OFF_W5);
  USHORT* W6p = (USHORT*)(ws + OFF_W6);
  USHORT* Wop = (USHORT*)(ws + OFF_WO);

  dim3 pgrid(544, 11, 1);
  vq_prep_kernel<<<pgrid, 256, 0, stream>>>(
      x, fc1w, fc2w, fc3w, muw, fc4w, fc5w, fc6w, outw, embed,
      W1p, W2p, W3p, Wmup, Wep, W4p, W5p, W6p, Wop, enorm, counts, lsum);

  vq_main_kernel<<<2048, 256, 0, stream>>>(
      x, c, fc1b, fc2b, fc3b, mub, fc4b, fc5b, fc6b, outb, embed,
      W1p, W2p, W3p, Wmup, Wep, enorm,
      W4p, W5p, W6p, Wop, counts, lsum, d_out);

  vq_fin_kernel<<<1, 256, 0, stream>>>(x, counts, lsum, d_out);
}

// Round 7
// 1213.125 us; speedup vs baseline: 1.0912x; 1.0032x over previous
//
#include <hip/hip_runtime.h>

// ---------------------------------------------------------------------------
// PoseVQVAE fused forward. DUAL-MODE storage dtype (f32 vs bf16) sniffed
// on-device. Math core: bf16 MFMA 32x32x16 (main path), 16x16x32 (mu),
// encoder 3-plane trunc-splits (split on READ from f32 LDS acts),
// decoder 1-plane bf16.
// Round 7: main kernel reverted BYTE-FOR-BYTE to the round-2 text (last
// passing, 1052us main). R5/R6's fc1 pipeline + B ping-pong are dropped
// entirely (shared unlocalized correctness bug, identical absmax both
// rounds). Only change: prep does 2 elements/thread (grid halved), which
// is bit-identical output per element.
// ---------------------------------------------------------------------------

using short8 = __attribute__((ext_vector_type(8))) short;
using f32x4  = __attribute__((ext_vector_type(4))) float;
using f32x16 = __attribute__((ext_vector_type(16))) float;

#define USHORT unsigned short
#define UINT   unsigned int

// plane sizes in ushorts
#define PS_W1  139264   // 544*256
#define PS_W2  65536    // 256*256
#define PS_MU  16384    // 256*64
#define PS_WE  65536    // 64*1024

// LDS geometry
#define STRF 260        // f32 activation stride
#define STRA 360        // dec sA stride (ushort)
#define STRB 264        // dec sB stride (ushort)

// ---- ws layout (bytes), 64B-aligned ----
static const size_t OFF_COUNTS = 262144;    // 1024*4
static const size_t OFF_LOSS   = 266240;    // 4 (+pad)
static const size_t OFF_ENORM  = 266304;    // 1024*4
static const size_t OFF_W1     = 270400;    // 3 planes * 139264 * 2 = 835584
static const size_t OFF_W2     = 1105984;   // 3*65536*2 = 393216
static const size_t OFF_W3     = 1499200;   // 393216
static const size_t OFF_WMU    = 1892416;   // 3*16384*2 = 98304
static const size_t OFF_WE     = 1990720;   // 3*65536*2 = 393216
static const size_t OFF_W4     = 2383936;   // 352*256*2 = 180224
static const size_t OFF_W5     = 2564160;   // 131072
static const size_t OFF_W6     = 2695232;   // 131072
static const size_t OFF_WO     = 2826304;   // 256*288*2 = 147456 -> end ~2.98MB

__device__ __forceinline__ float b2f(USHORT u){
  return __uint_as_float(((UINT)u) << 16);
}
__device__ __forceinline__ USHORT f2b(float f){            // RNE f32->bf16
  UINT u = __float_as_uint(f);
  u += 0x7fffu + ((u >> 16) & 1u);
  return (USHORT)(u >> 16);
}
__device__ __forceinline__ float loadF(const void* p, long i, int f32m){
  if (f32m) return ((const float*)p)[i];
  return b2f(((const USHORT*)p)[i]);
}
// RNE 3-plane split (prep / weights; validated numerics)
__device__ __forceinline__ void split3(float h, USHORT& a, USHORT& b, USHORT& c){
  a = f2b(h); float r = h - b2f(a);
  b = f2b(r); r -= b2f(b);
  c = f2b(r);
}
// truncation 3-plane split (hot path): a+b+c == h to ~2^-24, 7-9 VALU ops
__device__ __forceinline__ void splitT(float h, USHORT& a, USHORT& b, USHORT& c){
  UINT u = __float_as_uint(h);
  a = (USHORT)(u >> 16);
  float r = h - __uint_as_float(u & 0xffff0000u);
  UINT v = __float_as_uint(r);
  b = (USHORT)(v >> 16);
  float r2 = r - __uint_as_float(v & 0xffff0000u);
  c = f2b(r2);
}
__device__ __forceinline__ f32x4 mfma16(short8 a, short8 b, f32x4 c){
  return __builtin_amdgcn_mfma_f32_16x16x32_bf16(a, b, c, 0, 0, 0);
}
__device__ __forceinline__ f32x16 mfma32(short8 a, short8 b, f32x16 c){
  return __builtin_amdgcn_mfma_f32_32x32x16_bf16(a, b, c, 0, 0, 0);
}
__device__ __forceinline__ void zero16(f32x16& v){
  #pragma unroll
  for (int i = 0; i < 16; ++i) v[i] = 0.f;
}
// build 3 A-planes from 8 consecutive f32 in LDS (trunc split)
__device__ __forceinline__ void splitAT(const float* p, short8& A0, short8& A1, short8& A2){
  #pragma unroll
  for (int j = 0; j < 8; ++j){
    USHORT t0, t1, t2; splitT(p[j], t0, t1, t2);
    A0[j] = (short)t0; A1[j] = (short)t1; A2[j] = (short)t2;
  }
}
// dtype sniff (wave-uniform): bf16 storage -> low u16 exponent in [117,130]
__device__ __forceinline__ int detect_f32(const void* x){
  UINT u = ((const UINT*)x)[threadIdx.x & 63];
  int e = (int)((u >> 7) & 0xFFu);
  unsigned long long m = __ballot(e >= 117 && e <= 130);
  return __popcll(m) < 32;
}

// ---------------------------------------------------------------------------
// prep: repack weights into [K/8][N][8] bf16 planes; enorm; zero accums.
// ---------------------------------------------------------------------------
__device__ __forceinline__ void fillW(USHORT* dst, const void* src,
                                      int Kpad, int N, int Ksrc, int Nsrc,
                                      int srcStride, bool kmajor, int t,
                                      int f32m, int planes)
{
  int total = Kpad * N;
  if (t >= total) return;
  int j = t & 7, rest = t >> 3;
  int n = rest % N, kg = rest / N;
  int k = kg*8 + j;
  float v = 0.f;
  if (k < Ksrc && n < Nsrc)
    v = loadF(src, kmajor ? (long)k*srcStride + n : (long)n*srcStride + k, f32m);
  if (planes == 1){ dst[t] = f2b(v); return; }
  USHORT t0, t1, t2; split3(v, t0, t1, t2);
  dst[t] = t0; dst[total + t] = t1; dst[2*total + t] = t2;
}

__global__ void vq_prep_kernel(
    const void* xx,
    const void* fc1w, const void* fc2w, const void* fc3w,
    const void* muw,  const void* fc4w, const void* fc5w,
    const void* fc6w, const void* outw, const void* embed,
    USHORT* W1p, USHORT* W2p, USHORT* W3p, USHORT* Wmup, USHORT* Wep,
    USHORT* W4p, USHORT* W5p, USHORT* W6p, USHORT* Wop,
    float* enorm, UINT* counts, float* loss_sum)
{
  int f32m = detect_f32(xx);
  int t0 = (blockIdx.x * 256 + threadIdx.x) * 2;
  #pragma unroll
  for (int e = 0; e < 2; ++e){
    int t = t0 + e;
    switch (blockIdx.y){
      case 0: fillW(W1p,  fc1w, 544, 256, 534, 256, 534, false, t, f32m, 3); break;
      case 1: fillW(W2p,  fc2w, 256, 256, 256, 256, 256, false, t, f32m, 3); break;
      case 2: fillW(W3p,  fc3w, 256, 256, 256, 256, 256, false, t, f32m, 3); break;
      case 3: fillW(Wmup, muw,  256,  64, 256,  64, 256, false, t, f32m, 3); break;
      case 4: fillW(Wep,  embed, 64, 1024, 64, 1024, 1024, true, t, f32m, 3); break;
      case 5: fillW(W4p,  fc4w, 352, 256, 331, 256, 331, false, t, f32m, 1); break;
      case 6: fillW(W5p,  fc5w, 256, 256, 256, 256, 256, false, t, f32m, 1); break;
      case 7: fillW(W6p,  fc6w, 256, 256, 256, 256, 256, false, t, f32m, 1); break;
      case 8: fillW(Wop,  outw, 256, 288, 256, 267, 256, false, t, f32m, 1); break;
      case 9:
        if (t < 1024){
          double s = 0.0;
          for (int l = 0; l < 64; ++l){
            double ev = (double)loadF(embed, (long)l*1024 + t, f32m); s += ev*ev;
          }
          enorm[t] = (float)s;
        }
        break;
      case 10:
        if (t < 1024) counts[t] = 0u;
        if (t == 1024) *loss_sum = 0.f;
        break;
    }
  }
}

// ---------------------------------------------------------------------------
// fused main: 32 rows/block, 256 threads (4 waves).
// Wave w owns ALL 32 rows x 64-col slice (tb0 = w*64) -> B read once/block.
// MFMA 32x32x16: A row = lane&31, k = (lane>>5)*8 + j;
//                C/D: col = lane&31, row = (reg&3) + 8*(reg>>2) + 4*(lane>>5)
// ---------------------------------------------------------------------------
__global__ __launch_bounds__(256, 4) void vq_main_kernel(
    const void* __restrict__ x,  const void* __restrict__ cc,
    const void* __restrict__ b1, const void* __restrict__ b2,
    const void* __restrict__ b3, const void* __restrict__ bmu,
    const void* __restrict__ b4, const void* __restrict__ b5,
    const void* __restrict__ b6, const void* __restrict__ bo,
    const void* __restrict__ embed,
    const USHORT* __restrict__ W1p, const USHORT* __restrict__ W2p,
    const USHORT* __restrict__ W3p, const USHORT* __restrict__ Wmup,
    const USHORT* __restrict__ Wep, const float* __restrict__ enorm,
    const USHORT* __restrict__ W4p, const USHORT* __restrict__ W5p,
    const USHORT* __restrict__ W6p, const USHORT* __restrict__ Wop,
    UINT* __restrict__ counts, float* __restrict__ loss_sum,
    void* __restrict__ out)
{
  // union buffer: enc f32 acts [32][260] (33280B) ALIASED with
  // dec sA [32][360] bf16 (23040B) + sB [32][264] bf16 (16896B) = 39936B
  __shared__ __align__(16) char U[39936];
  __shared__ float rMin[4][32];
  __shared__ int   rCode[4][32];        // rCode[0] becomes the codes[] after combine
  float*  sF = (float*)U;
  USHORT* sA = (USHORT*)U;
  USHORT* sB = (USHORT*)(U + 23040);

  const int f32m = detect_f32(x);
  const int tid  = threadIdx.x;
  const int w    = tid >> 6;
  const int lane = tid & 63;
  const int hi   = lane >> 5;
  const int nn   = lane & 31;
  const int quad = lane >> 4;
  const int l16  = lane & 15;
  const int tb0  = w * 64;                   // this wave's 64-col slice
  const long gbase = (long)blockIdx.x * 32;
  const long gr    = gbase + nn;             // global row for A fragments

  f32x16 acc0, acc1;
  zero16(acc0); zero16(acc1);

  // ================= encoder =================
  // ---- fc1: K=544 (34 k-steps of 16); A from global, trunc 3-plane split
  for (int ks = 0; ks < 34; ++ks){
    short8 A0, A1, A2;
    if (f32m){
      #pragma unroll
      for (int j = 0; j < 8; ++j){
        int col = ks*16 + hi*8 + j;
        float v = 0.f;
        if (col < 267)      v = ((const float*)x)[gr*267 + col];
        else if (col < 534) v = ((const float*)cc)[gr*267 + (col - 267)];
        USHORT t0, t1, t2; splitT(v, t0, t1, t2);
        A0[j] = (short)t0; A1[j] = (short)t1; A2[j] = (short)t2;
      }
    } else {
      #pragma unroll
      for (int j = 0; j < 8; ++j){
        int col = ks*16 + hi*8 + j;
        USHORT u = 0;
        if (col < 267)      u = ((const USHORT*)x)[gr*267 + col];
        else if (col < 534) u = ((const USHORT*)cc)[gr*267 + (col - 267)];
        A0[j] = (short)u;
      }
    }
    const USHORT* bp = W1p + (((ks*2 + hi)*256) + tb0 + nn)*8;
    short8 B00 = *(const short8*)bp;
    short8 B01 = *(const short8*)(bp + 256);
    if (!f32m){
      acc0 = mfma32(A0, B00, acc0); acc1 = mfma32(A0, B01, acc1);
    } else {
      short8 B10 = *(const short8*)(bp + PS_W1);
      short8 B11 = *(const short8*)(bp + PS_W1 + 256);
      short8 B20 = *(const short8*)(bp + 2*PS_W1);
      short8 B21 = *(const short8*)(bp + 2*PS_W1 + 256);
      acc0 = mfma32(A0, B00, acc0); acc1 = mfma32(A0, B01, acc1);
      acc0 = mfma32(A1, B00, acc0); acc1 = mfma32(A1, B01, acc1);
      acc0 = mfma32(A2, B00, acc0); acc1 = mfma32(A2, B01, acc1);
      acc0 = mfma32(A0, B10, acc0); acc1 = mfma32(A0, B11, acc1);
      acc0 = mfma32(A1, B10, acc0); acc1 = mfma32(A1, B11, acc1);
      acc0 = mfma32(A0, B20, acc0); acc1 = mfma32(A0, B21, acc1);
    }
  }
  {
    float bs0 = loadF(b1, tb0 + nn, f32m);
    float bs1 = loadF(b1, tb0 + 32 + nn, f32m);
    #pragma unroll
    for (int reg = 0; reg < 16; ++reg){
      int r = (reg&3) + 8*(reg>>2) + 4*hi;
      sF[r*STRF + tb0 + nn]      = fmaxf(acc0[reg] + bs0, 0.f);
      sF[r*STRF + tb0 + 32 + nn] = fmaxf(acc1[reg] + bs1, 0.f);
    }
  }
  __syncthreads();

  // ---- fc2, fc3: in-place f32 LDS, trunc-split-on-read, K=256 (16 k-steps)
  for (int layer = 0; layer < 2; ++layer){
    const USHORT* Wp = layer ? W3p : W2p;
    const void*   bb = layer ? (const void*)b3 : (const void*)b2;
    zero16(acc0); zero16(acc1);
    #pragma unroll 2
    for (int ks = 0; ks < 16; ++ks){
      short8 A0, A1, A2;
      splitAT(&sF[nn*STRF + ks*16 + hi*8], A0, A1, A2);
      const USHORT* bp = Wp + (((ks*2 + hi)*256) + tb0 + nn)*8;
      short8 B00 = *(const short8*)bp;
      short8 B01 = *(const short8*)(bp + 256);
      acc0 = mfma32(A0, B00, acc0); acc1 = mfma32(A0, B01, acc1);
      acc0 = mfma32(A1, B00, acc0); acc1 = mfma32(A1, B01, acc1);
      acc0 = mfma32(A2, B00, acc0); acc1 = mfma32(A2, B01, acc1);
      if (f32m){
        short8 B10 = *(const short8*)(bp + PS_W2);
        short8 B11 = *(const short8*)(bp + PS_W2 + 256);
        short8 B20 = *(const short8*)(bp + 2*PS_W2);
        short8 B21 = *(const short8*)(bp + 2*PS_W2 + 256);
        acc0 = mfma32(A0, B10, acc0); acc1 = mfma32(A0, B11, acc1);
        acc0 = mfma32(A1, B10, acc0); acc1 = mfma32(A1, B11, acc1);
        acc0 = mfma32(A0, B20, acc0); acc1 = mfma32(A0, B21, acc1);
      }
    }
    __syncthreads();
    {
      float bs0 = loadF(bb, tb0 + nn, f32m);
      float bs1 = loadF(bb, tb0 + 32 + nn, f32m);
      #pragma unroll
      for (int reg = 0; reg < 16; ++reg){
        int r = (reg&3) + 8*(reg>>2) + 4*hi;
        sF[r*STRF + tb0 + nn]      = fmaxf(acc0[reg] + bs0, 0.f);
        sF[r*STRF + tb0 + 32 + nn] = fmaxf(acc1[reg] + bs1, 0.f);
      }
    }
    __syncthreads();
  }

  // ---- mu: N=64, 16x16x32 (wave w -> 16-col tile), dual row-groups, no relu
  {
    f32x4 am0, am1;
    #pragma unroll
    for (int i = 0; i < 4; ++i){ am0[i] = 0.f; am1[i] = 0.f; }
    #pragma unroll 2
    for (int kc = 0; kc < 8; ++kc){
      short8 A0a, A1a, A2a, A0b, A1b, A2b;
      splitAT(&sF[l16*STRF + kc*32 + quad*8],        A0a, A1a, A2a);
      splitAT(&sF[(l16 + 16)*STRF + kc*32 + quad*8], A0b, A1b, A2b);
      const USHORT* bp = Wmup + ((kc*4 + quad)*64 + w*16 + l16)*8;
      short8 Bm0 = *(const short8*)bp;
      am0 = mfma16(A0a, Bm0, am0); am1 = mfma16(A0b, Bm0, am1);
      am0 = mfma16(A1a, Bm0, am0); am1 = mfma16(A1b, Bm0, am1);
      am0 = mfma16(A2a, Bm0, am0); am1 = mfma16(A2b, Bm0, am1);
      if (f32m){
        short8 Bm1 = *(const short8*)(bp + PS_MU);
        am0 = mfma16(A0a, Bm1, am0); am1 = mfma16(A0b, Bm1, am1);
        am0 = mfma16(A1a, Bm1, am0); am1 = mfma16(A1b, Bm1, am1);
        short8 Bm2 = *(const short8*)(bp + 2*PS_MU);
        am0 = mfma16(A0a, Bm2, am0); am1 = mfma16(A0b, Bm2, am1);
      }
    }
    __syncthreads();
    float bm = loadF(bmu, w*16 + l16, f32m);
    #pragma unroll
    for (int r = 0; r < 4; ++r){
      sF[(quad*4 + r)*STRF + w*16 + l16]        = am0[r] + bm;
      sF[(quad*4 + r + 16)*STRF + w*16 + l16]   = am1[r] + bm;
    }
    __syncthreads();
  }

  // ---- VQ: argmin_k(||e_k||^2 - 2 mu.e_k); wave w scans codes [w*256, +256)
  {
    short8 MA0[4], MA1[4], MA2[4];
    #pragma unroll
    for (int ks = 0; ks < 4; ++ks)
      splitAT(&sF[nn*STRF + ks*16 + hi*8], MA0[ks], MA1[ks], MA2[ks]);
    float minv[16]; int minc[16];
    #pragma unroll
    for (int i = 0; i < 16; ++i){ minv[i] = 3.4e38f; minc[i] = 0; }
    for (int tt = 0; tt < 8; ++tt){              // 32 codes per tile
      int cb = w*256 + tt*32;
      f32x16 ad; zero16(ad);
      #pragma unroll
      for (int ks = 0; ks < 4; ++ks){
        const USHORT* bp = Wep + (((ks*2 + hi)*1024) + cb + nn)*8;
        short8 B0 = *(const short8*)bp;
        ad = mfma32(MA0[ks], B0, ad);
        ad = mfma32(MA1[ks], B0, ad);
        ad = mfma32(MA2[ks], B0, ad);
        if (f32m){
          short8 B1 = *(const short8*)(bp + PS_WE);
          ad = mfma32(MA0[ks], B1, ad);
          ad = mfma32(MA1[ks], B1, ad);
          short8 B2 = *(const short8*)(bp + 2*PS_WE);
          ad = mfma32(MA0[ks], B2, ad);
        }
      }
      int code = cb + nn;
      float en = enorm[code];
      #pragma unroll
      for (int reg = 0; reg < 16; ++reg){
        float d = en - 2.f*ad[reg];
        if (d < minv[reg] || (d == minv[reg] && code < minc[reg])){ minv[reg] = d; minc[reg] = code; }
      }
    }
    // reduce across the 32 code-lanes of each half (rows differ by half!)
    #pragma unroll
    for (int off = 16; off >= 1; off >>= 1){
      #pragma unroll
      for (int reg = 0; reg < 16; ++reg){
        float ov = __shfl_xor(minv[reg], off, 64);
        int   oc = __shfl_xor(minc[reg], off, 64);
        if (ov < minv[reg] || (ov == minv[reg] && oc < minc[reg])){ minv[reg] = ov; minc[reg] = oc; }
      }
    }
    if (nn == 0){
      #pragma unroll
      for (int reg = 0; reg < 16; ++reg){
        int r = (reg&3) + 8*(reg>>2) + 4*hi;
        rMin[w][r]  = minv[reg];
        rCode[w][r] = minc[reg];
      }
    }
  }
  __syncthreads();

  // combine the 4 wave-quarters (ascending -> lowest-index tie-break), histogram
  if (tid < 32){
    float bv = rMin[0][tid]; int bc = rCode[0][tid];
    #pragma unroll
    for (int ww = 1; ww < 4; ++ww){
      float v = rMin[ww][tid]; int cd = rCode[ww][tid];
      if (v < bv || (v == bv && cd < bc)){ bv = v; bc = cd; }
    }
    rCode[0][tid] = bc;                      // codes[]
    atomicAdd(&counts[bc], 1u);
  }
  __syncthreads();

  // ---- loss: thread t -> (row = t>>3, dims (t&7)*8 ..+8)
  {
    int lrow = tid >> 3;
    int j0 = (tid & 7) * 8;
    int code = rCode[0][lrow];
    float lp = 0.f;
    #pragma unroll
    for (int jj = 0; jj < 8; ++jj){
      int l = j0 + jj;
      float qv = loadF(embed, (long)l*1024 + code, f32m);
      float d = qv - sF[lrow*STRF + l];
      lp += d*d;
    }
    #pragma unroll
    for (int off = 32; off >= 1; off >>= 1) lp += __shfl_xor(lp, off, 64);
    if (lane == 0) rMin[0][w] = lp;
  }
  __syncthreads();                            // all sF reads done; sA may be written
  if (tid == 0)
    atomicAdd(loss_sum, rMin[0][0] + rMin[0][1] + rMin[0][2] + rMin[0][3]);

  // ================= decoder (bf16 1-plane) =================
  // stage s2 = [q | c | 0pad], width 360 (331 used)
  {
    // q: from Wep plane0 ( == f2b(embed) ), 8 contiguous short8 per row
    int rr = tid >> 3, jg = tid & 7;
    int code = rCode[0][rr];
    short8 qv = *(const short8*)(Wep + ((long)jg*1024 + code)*8);
    *(short8*)&sA[rr*STRA + jg*8] = qv;
  }
  for (int rr = w*8; rr < w*8 + 8; ++rr){
    long grow = gbase + rr;
    for (int col = 64 + lane; col < 360; col += 64){
      float v = (col < 331) ? loadF(cc, grow*267 + (col - 64), f32m) : 0.f;
      sA[rr*STRA + col] = f2b(v);
    }
  }
  __syncthreads();

  // ---- fc4: K=352 (22 k-steps) : sA -> sB
  zero16(acc0); zero16(acc1);
  #pragma unroll 2
  for (int ks = 0; ks < 22; ++ks){
    short8 A = *(const short8*)&sA[nn*STRA + ks*16 + hi*8];
    const USHORT* bp = W4p + (((ks*2 + hi)*256) + tb0 + nn)*8;
    acc0 = mfma32(A, *(const short8*)bp,         acc0);
    acc1 = mfma32(A, *(const short8*)(bp + 256), acc1);
  }
  {
    float bs0 = loadF(b4, tb0 + nn, f32m);
    float bs1 = loadF(b4, tb0 + 32 + nn, f32m);
    #pragma unroll
    for (int reg = 0; reg < 16; ++reg){
      int r = (reg&3) + 8*(reg>>2) + 4*hi;
      sB[r*STRB + tb0 + nn]      = f2b(fmaxf(acc0[reg] + bs0, 0.f));
      sB[r*STRB + tb0 + 32 + nn] = f2b(fmaxf(acc1[reg] + bs1, 0.f));
    }
  }
  __syncthreads();

  // ---- fc5: sB -> sA (in-place-flip: barrier between read and write)
  zero16(acc0); zero16(acc1);
  #pragma unroll 4
  for (int ks = 0; ks < 16; ++ks){
    short8 A = *(const short8*)&sB[nn*STRB + ks*16 + hi*8];
    const USHORT* bp = W5p + (((ks*2 + hi)*256) + tb0 + nn)*8;
    acc0 = mfma32(A, *(const short8*)bp,         acc0);
    acc1 = mfma32(A, *(const short8*)(bp + 256), acc1);
  }
  __syncthreads();
  {
    float bs0 = loadF(b5, tb0 + nn, f32m);
    float bs1 = loadF(b5, tb0 + 32 + nn, f32m);
    #pragma unroll
    for (int reg = 0; reg < 16; ++reg){
      int r = (reg&3) + 8*(reg>>2) + 4*hi;
      sA[r*STRA + tb0 + nn]      = f2b(fmaxf(acc0[reg] + bs0, 0.f));
      sA[r*STRA + tb0 + 32 + nn] = f2b(fmaxf(acc1[reg] + bs1, 0.f));
    }
  }
  __syncthreads();

  // ---- fc6: sA -> sB
  zero16(acc0); zero16(acc1);
  #pragma unroll 4
  for (int ks = 0; ks < 16; ++ks){
    short8 A = *(const short8*)&sA[nn*STRA + ks*16 + hi*8];
    const USHORT* bp = W6p + (((ks*2 + hi)*256) + tb0 + nn)*8;
    acc0 = mfma32(A, *(const short8*)bp,         acc0);
    acc1 = mfma32(A, *(const short8*)(bp + 256), acc1);
  }
  __syncthreads();
  {
    float bs0 = loadF(b6, tb0 + nn, f32m);
    float bs1 = loadF(b6, tb0 + 32 + nn, f32m);
    #pragma unroll
    for (int reg = 0; reg < 16; ++reg){
      int r = (reg&3) + 8*(reg>>2) + 4*hi;
      sB[r*STRB + tb0 + nn]      = f2b(fmaxf(acc0[reg] + bs0, 0.f));
      sB[r*STRB + tb0 + 32 + nn] = f2b(fmaxf(acc1[reg] + bs1, 0.f));
    }
  }
  __syncthreads();

  // ---- out: N=288 padded (267 real); waves 0-2: 2 tiles, wave 3: 3 tiles
  {
    f32x16 acco0, acco1, acco2;
    zero16(acco0); zero16(acco1); zero16(acco2);
    #pragma unroll 2
    for (int ks = 0; ks < 16; ++ks){
      short8 A = *(const short8*)&sB[nn*STRB + ks*16 + hi*8];
      const USHORT* bp = Wop + (((ks*2 + hi)*288) + w*64 + nn)*8;
      acco0 = mfma32(A, *(const short8*)bp,         acco0);
      acco1 = mfma32(A, *(const short8*)(bp + 256), acco1);
      if (w == 3) acco2 = mfma32(A, *(const short8*)(bp + 512), acco2);
    }
    int ntiles = (w == 3) ? 3 : 2;
    #pragma unroll
    for (int t = 0; t < 3; ++t){
      if (t < ntiles){
        int col = w*64 + t*32 + nn;
        if (col < 267){
          float bias = loadF(bo, col, f32m);
          f32x16& a = (t == 0) ? acco0 : (t == 1) ? acco1 : acco2;
          #pragma unroll
          for (int reg = 0; reg < 16; ++reg){
            int r = (reg&3) + 8*(reg>>2) + 4*hi;
            long oi = (gbase + r)*267 + col;
            float val = a[reg] + bias;
            if (f32m) ((float*)out)[oi] = val;
            else      ((USHORT*)out)[oi] = f2b(val);
          }
        }
      }
    }
  }
}

// ---------------------------------------------------------------------------
// finalize: loss mean + perplexity from histogram
// ---------------------------------------------------------------------------
__global__ void vq_fin_kernel(const void* __restrict__ x,
                              const UINT* __restrict__ counts,
                              const float* __restrict__ loss_sum,
                              void* __restrict__ out)
{
  __shared__ float red[4];
  int f32m = detect_f32(x);
  int tid = threadIdx.x;
  float Hl = 0.f;
  for (int k = tid; k < 1024; k += 256){
    float p = (float)counts[k] * (1.f/65536.f);
    Hl -= p * logf(p + 1e-10f);
  }
  #pragma unroll
  for (int off = 32; off >= 1; off >>= 1) Hl += __shfl_xor(Hl, off, 64);
  if ((tid & 63) == 0) red[tid >> 6] = Hl;
  __syncthreads();
  if (tid == 0){
    float H = red[0] + red[1] + red[2] + red[3];
    float loss = *loss_sum * (1.f/4194304.f);   // /(B*L)
    float ppx  = expf(H);
    size_t base = (size_t)65536*267;
    if (f32m){
      ((float*)out)[base]     = loss;
      ((float*)out)[base + 1] = ppx;
    } else {
      ((USHORT*)out)[base]     = f2b(loss);
      ((USHORT*)out)[base + 1] = f2b(ppx);
    }
  }
}

// ---------------------------------------------------------------------------
extern "C" void kernel_launch(void* const* d_in, const int* in_sizes, int n_in,
                              void* d_out, int out_size, void* d_ws, size_t ws_size,
                              hipStream_t stream)
{
  const void* x    = d_in[0];
  const void* c    = d_in[1];
  const void* fc1w = d_in[2];
  const void* fc1b = d_in[3];
  const void* fc2w = d_in[4];
  const void* fc2b = d_in[5];
  const void* fc3w = d_in[6];
  const void* fc3b = d_in[7];
  const void* muw  = d_in[8];
  const void* mub  = d_in[9];
  const void* fc4w = d_in[10];
  const void* fc4b = d_in[11];
  const void* fc5w = d_in[12];
  const void* fc5b = d_in[13];
  const void* fc6w = d_in[14];
  const void* fc6b = d_in[15];
  const void* outw = d_in[16];
  const void* outb = d_in[17];
  const void* embed= d_in[18];

  char* ws = (char*)d_ws;
  UINT*   counts = (UINT*)  (ws + OFF_COUNTS);
  float*  lsum   = (float*) (ws + OFF_LOSS);
  float*  enorm  = (float*) (ws + OFF_ENORM);
  USHORT* W1p = (USHORT*)(ws + OFF_W1);
  USHORT* W2p = (USHORT*)(ws + OFF_W2);
  USHORT* W3p = (USHORT*)(ws + OFF_W3);
  USHORT* Wmup= (USHORT*)(ws + OFF_WMU);
  USHORT* Wep = (USHORT*)(ws + OFF_WE);
  USHORT* W4p = (USHORT*)(ws + OFF_W4);
  USHORT* W5p = (USHORT*)(ws + OFF_W5);
  USHORT* W6p = (USHORT*)(ws + OFF_W6);
  USHORT* Wop = (USHORT*)(ws + OFF_WO);

  // 2 elements/thread -> 272 blocks covers the largest table (544*256 elems)
  dim3 pgrid(272, 11, 1);
  vq_prep_kernel<<<pgrid, 256, 0, stream>>>(
      x, fc1w, fc2w, fc3w, muw, fc4w, fc5w, fc6w, outw, embed,
      W1p, W2p, W3p, Wmup, Wep, W4p, W5p, W6p, Wop, enorm, counts, lsum);

  vq_main_kernel<<<2048, 256, 0, stream>>>(
      x, c, fc1b, fc2b, fc3b, mub, fc4b, fc5b, fc6b, outb, embed,
      W1p, W2p, W3p, Wmup, Wep, enorm,
      W4p, W5p, W6p, Wop, counts, lsum, d_out);

  vq_fin_kernel<<<1, 256, 0, stream>>>(x, counts, lsum, d_out);
}

// Round 8
// 1160.507 us; speedup vs baseline: 1.1407x; 1.0453x over previous
//
#include <hip/hip_runtime.h>

// ---------------------------------------------------------------------------
// PoseVQVAE fused forward. DUAL-MODE storage dtype (f32 vs bf16) sniffed
// on-device. Math core: bf16 MFMA 32x32x16 (main path), 16x16x32 (mu),
// encoder 3-plane trunc-splits (split on READ from f32 LDS acts),
// decoder 1-plane bf16.
// Round 8 = round-7 (passing baseline) + fc1 LDS staging:
//   x/c staged through the union LDS buffer in two 272-col chunks with
//   coalesced 64-lane bursts (independent loads -> HBM latency hidden),
//   then fc1 A-reads come from LDS. Values round-trip the same f32 bits
//   and the MFMA order is untouched -> BIT-IDENTICAL results to round 7.
//   (R5/R6's fc1 pipeline / B ping-pong remain quarantined.)
// ---------------------------------------------------------------------------

using short8 = __attribute__((ext_vector_type(8))) short;
using f32x4  = __attribute__((ext_vector_type(4))) float;
using f32x16 = __attribute__((ext_vector_type(16))) float;

#define USHORT unsigned short
#define UINT   unsigned int

// plane sizes in ushorts
#define PS_W1  139264   // 544*256
#define PS_W2  65536    // 256*256
#define PS_MU  16384    // 256*64
#define PS_WE  65536    // 64*1024

// LDS geometry
#define STRF 260        // f32 activation stride
#define STRX 276        // fc1 staging stride (f32; 276*4=1104B, 16B-aligned rows)
#define STRA 360        // dec sA stride (ushort)
#define STRB 264        // dec sB stride (ushort)

// ---- ws layout (bytes), 64B-aligned ----
static const size_t OFF_COUNTS = 262144;    // 1024*4
static const size_t OFF_LOSS   = 266240;    // 4 (+pad)
static const size_t OFF_ENORM  = 266304;    // 1024*4
static const size_t OFF_W1     = 270400;    // 3 planes * 139264 * 2 = 835584
static const size_t OFF_W2     = 1105984;   // 3*65536*2 = 393216
static const size_t OFF_W3     = 1499200;   // 393216
static const size_t OFF_WMU    = 1892416;   // 3*16384*2 = 98304
static const size_t OFF_WE     = 1990720;   // 3*65536*2 = 393216
static const size_t OFF_W4     = 2383936;   // 352*256*2 = 180224
static const size_t OFF_W5     = 2564160;   // 131072
static const size_t OFF_W6     = 2695232;   // 131072
static const size_t OFF_WO     = 2826304;   // 256*288*2 = 147456 -> end ~2.98MB

__device__ __forceinline__ float b2f(USHORT u){
  return __uint_as_float(((UINT)u) << 16);
}
__device__ __forceinline__ USHORT f2b(float f){            // RNE f32->bf16
  UINT u = __float_as_uint(f);
  u += 0x7fffu + ((u >> 16) & 1u);
  return (USHORT)(u >> 16);
}
__device__ __forceinline__ float loadF(const void* p, long i, int f32m){
  if (f32m) return ((const float*)p)[i];
  return b2f(((const USHORT*)p)[i]);
}
// RNE 3-plane split (prep / weights; validated numerics)
__device__ __forceinline__ void split3(float h, USHORT& a, USHORT& b, USHORT& c){
  a = f2b(h); float r = h - b2f(a);
  b = f2b(r); r -= b2f(b);
  c = f2b(r);
}
// truncation 3-plane split (hot path): a+b+c == h to ~2^-24, 7-9 VALU ops
__device__ __forceinline__ void splitT(float h, USHORT& a, USHORT& b, USHORT& c){
  UINT u = __float_as_uint(h);
  a = (USHORT)(u >> 16);
  float r = h - __uint_as_float(u & 0xffff0000u);
  UINT v = __float_as_uint(r);
  b = (USHORT)(v >> 16);
  float r2 = r - __uint_as_float(v & 0xffff0000u);
  c = f2b(r2);
}
__device__ __forceinline__ f32x4 mfma16(short8 a, short8 b, f32x4 c){
  return __builtin_amdgcn_mfma_f32_16x16x32_bf16(a, b, c, 0, 0, 0);
}
__device__ __forceinline__ f32x16 mfma32(short8 a, short8 b, f32x16 c){
  return __builtin_amdgcn_mfma_f32_32x32x16_bf16(a, b, c, 0, 0, 0);
}
__device__ __forceinline__ void zero16(f32x16& v){
  #pragma unroll
  for (int i = 0; i < 16; ++i) v[i] = 0.f;
}
// build 3 A-planes from 8 consecutive f32 in LDS (trunc split)
__device__ __forceinline__ void splitAT(const float* p, short8& A0, short8& A1, short8& A2){
  #pragma unroll
  for (int j = 0; j < 8; ++j){
    USHORT t0, t1, t2; splitT(p[j], t0, t1, t2);
    A0[j] = (short)t0; A1[j] = (short)t1; A2[j] = (short)t2;
  }
}
// dtype sniff (wave-uniform): bf16 storage -> low u16 exponent in [117,130]
__device__ __forceinline__ int detect_f32(const void* x){
  UINT u = ((const UINT*)x)[threadIdx.x & 63];
  int e = (int)((u >> 7) & 0xFFu);
  unsigned long long m = __ballot(e >= 117 && e <= 130);
  return __popcll(m) < 32;
}

// ---------------------------------------------------------------------------
// prep: repack weights into [K/8][N][8] bf16 planes; enorm; zero accums.
// ---------------------------------------------------------------------------
__device__ __forceinline__ void fillW(USHORT* dst, const void* src,
                                      int Kpad, int N, int Ksrc, int Nsrc,
                                      int srcStride, bool kmajor, int t,
                                      int f32m, int planes)
{
  int total = Kpad * N;
  if (t >= total) return;
  int j = t & 7, rest = t >> 3;
  int n = rest % N, kg = rest / N;
  int k = kg*8 + j;
  float v = 0.f;
  if (k < Ksrc && n < Nsrc)
    v = loadF(src, kmajor ? (long)k*srcStride + n : (long)n*srcStride + k, f32m);
  if (planes == 1){ dst[t] = f2b(v); return; }
  USHORT t0, t1, t2; split3(v, t0, t1, t2);
  dst[t] = t0; dst[total + t] = t1; dst[2*total + t] = t2;
}

__global__ void vq_prep_kernel(
    const void* xx,
    const void* fc1w, const void* fc2w, const void* fc3w,
    const void* muw,  const void* fc4w, const void* fc5w,
    const void* fc6w, const void* outw, const void* embed,
    USHORT* W1p, USHORT* W2p, USHORT* W3p, USHORT* Wmup, USHORT* Wep,
    USHORT* W4p, USHORT* W5p, USHORT* W6p, USHORT* Wop,
    float* enorm, UINT* counts, float* loss_sum)
{
  int f32m = detect_f32(xx);
  int t0 = (blockIdx.x * 256 + threadIdx.x) * 2;
  #pragma unroll
  for (int e = 0; e < 2; ++e){
    int t = t0 + e;
    switch (blockIdx.y){
      case 0: fillW(W1p,  fc1w, 544, 256, 534, 256, 534, false, t, f32m, 3); break;
      case 1: fillW(W2p,  fc2w, 256, 256, 256, 256, 256, false, t, f32m, 3); break;
      case 2: fillW(W3p,  fc3w, 256, 256, 256, 256, 256, false, t, f32m, 3); break;
      case 3: fillW(Wmup, muw,  256,  64, 256,  64, 256, false, t, f32m, 3); break;
      case 4: fillW(Wep,  embed, 64, 1024, 64, 1024, 1024, true, t, f32m, 3); break;
      case 5: fillW(W4p,  fc4w, 352, 256, 331, 256, 331, false, t, f32m, 1); break;
      case 6: fillW(W5p,  fc5w, 256, 256, 256, 256, 256, false, t, f32m, 1); break;
      case 7: fillW(W6p,  fc6w, 256, 256, 256, 256, 256, false, t, f32m, 1); break;
      case 8: fillW(Wop,  outw, 256, 288, 256, 267, 256, false, t, f32m, 1); break;
      case 9:
        if (t < 1024){
          double s = 0.0;
          for (int l = 0; l < 64; ++l){
            double ev = (double)loadF(embed, (long)l*1024 + t, f32m); s += ev*ev;
          }
          enorm[t] = (float)s;
        }
        break;
      case 10:
        if (t < 1024) counts[t] = 0u;
        if (t == 1024) *loss_sum = 0.f;
        break;
    }
  }
}

// ---------------------------------------------------------------------------
// fused main: 32 rows/block, 256 threads (4 waves).
// Wave w owns ALL 32 rows x 64-col slice (tb0 = w*64) -> B read once/block.
// MFMA 32x32x16: A row = lane&31, k = (lane>>5)*8 + j;
//                C/D: col = lane&31, row = (reg&3) + 8*(reg>>2) + 4*(lane>>5)
// ---------------------------------------------------------------------------
__global__ __launch_bounds__(256, 4) void vq_main_kernel(
    const void* __restrict__ x,  const void* __restrict__ cc,
    const void* __restrict__ b1, const void* __restrict__ b2,
    const void* __restrict__ b3, const void* __restrict__ bmu,
    const void* __restrict__ b4, const void* __restrict__ b5,
    const void* __restrict__ b6, const void* __restrict__ bo,
    const void* __restrict__ embed,
    const USHORT* __restrict__ W1p, const USHORT* __restrict__ W2p,
    const USHORT* __restrict__ W3p, const USHORT* __restrict__ Wmup,
    const USHORT* __restrict__ Wep, const float* __restrict__ enorm,
    const USHORT* __restrict__ W4p, const USHORT* __restrict__ W5p,
    const USHORT* __restrict__ W6p, const USHORT* __restrict__ Wop,
    UINT* __restrict__ counts, float* __restrict__ loss_sum,
    void* __restrict__ out)
{
  // union buffer U (39936B), time-multiplexed:
  //   fc1:       sX staging [32][276] f32 (35328B)
  //   fc2..VQ:   sF acts    [32][260] f32 (33280B)
  //   decoder:   sA [32][360] bf16 (23040B) + sB [32][264] bf16 (16896B)
  __shared__ __align__(16) char U[39936];
  __shared__ float rMin[4][32];
  __shared__ int   rCode[4][32];        // rCode[0] becomes the codes[] after combine
  float*  sF = (float*)U;
  USHORT* sA = (USHORT*)U;
  USHORT* sB = (USHORT*)(U + 23040);

  const int f32m = detect_f32(x);
  const int tid  = threadIdx.x;
  const int w    = tid >> 6;
  const int lane = tid & 63;
  const int hi   = lane >> 5;
  const int nn   = lane & 31;
  const int quad = lane >> 4;
  const int l16  = lane & 15;
  const int tb0  = w * 64;                   // this wave's 64-col slice
  const long gbase = (long)blockIdx.x * 32;
  const long gr    = gbase + nn;             // global row for A fragments

  f32x16 acc0, acc1;
  zero16(acc0); zero16(acc1);

  // ================= encoder =================
  // ---- fc1: K=544 (34 k-steps of 16); A staged via LDS (f32 mode)
  if (f32m){
    float* sX = (float*)U;                   // dead before sF is first written
    #pragma unroll
    for (int ch = 0; ch < 2; ++ch){
      const int cb0 = ch * 272;
      // stage: wave w rows w*8..+7, coalesced 64-lane bursts, independent loads
      for (int rr = w*8; rr < w*8 + 8; ++rr){
        const float* xr = (const float*)x  + (gbase + rr)*267;
        const float* cr = (const float*)cc + (gbase + rr)*267;
        for (int c = lane; c < 272; c += 64){
          int gc = cb0 + c;
          float v = 0.f;
          if (gc < 267)      v = xr[gc];
          else if (gc < 534) v = cr[gc - 267];
          sX[rr*STRX + c] = v;
        }
      }
      __syncthreads();
      const int ksBeg = ch ? 17 : 0;
      const int ksEnd = ch ? 34 : 17;
      for (int ks = ksBeg; ks < ksEnd; ++ks){
        short8 A0, A1, A2;
        splitAT(&sX[nn*STRX + (ks*16 - cb0) + hi*8], A0, A1, A2);
        const USHORT* bp = W1p + (((ks*2 + hi)*256) + tb0 + nn)*8;
        short8 B00 = *(const short8*)bp;
        short8 B01 = *(const short8*)(bp + 256);
        short8 B10 = *(const short8*)(bp + PS_W1);
        short8 B11 = *(const short8*)(bp + PS_W1 + 256);
        short8 B20 = *(const short8*)(bp + 2*PS_W1);
        short8 B21 = *(const short8*)(bp + 2*PS_W1 + 256);
        acc0 = mfma32(A0, B00, acc0); acc1 = mfma32(A0, B01, acc1);
        acc0 = mfma32(A1, B00, acc0); acc1 = mfma32(A1, B01, acc1);
        acc0 = mfma32(A2, B00, acc0); acc1 = mfma32(A2, B01, acc1);
        acc0 = mfma32(A0, B10, acc0); acc1 = mfma32(A0, B11, acc1);
        acc0 = mfma32(A1, B10, acc0); acc1 = mfma32(A1, B11, acc1);
        acc0 = mfma32(A0, B20, acc0); acc1 = mfma32(A0, B21, acc1);
      }
      __syncthreads();   // all sX reads done before restage / sF write
    }
  } else {
    for (int ks = 0; ks < 34; ++ks){
      short8 A0;
      #pragma unroll
      for (int j = 0; j < 8; ++j){
        int col = ks*16 + hi*8 + j;
        USHORT u = 0;
        if (col < 267)      u = ((const USHORT*)x)[gr*267 + col];
        else if (col < 534) u = ((const USHORT*)cc)[gr*267 + (col - 267)];
        A0[j] = (short)u;
      }
      const USHORT* bp = W1p + (((ks*2 + hi)*256) + tb0 + nn)*8;
      short8 B00 = *(const short8*)bp;
      short8 B01 = *(const short8*)(bp + 256);
      acc0 = mfma32(A0, B00, acc0); acc1 = mfma32(A0, B01, acc1);
    }
  }
  {
    float bs0 = loadF(b1, tb0 + nn, f32m);
    float bs1 = loadF(b1, tb0 + 32 + nn, f32m);
    #pragma unroll
    for (int reg = 0; reg < 16; ++reg){
      int r = (reg&3) + 8*(reg>>2) + 4*hi;
      sF[r*STRF + tb0 + nn]      = fmaxf(acc0[reg] + bs0, 0.f);
      sF[r*STRF + tb0 + 32 + nn] = fmaxf(acc1[reg] + bs1, 0.f);
    }
  }
  __syncthreads();

  // ---- fc2, fc3: in-place f32 LDS, trunc-split-on-read, K=256 (16 k-steps)
  for (int layer = 0; layer < 2; ++layer){
    const USHORT* Wp = layer ? W3p : W2p;
    const void*   bb = layer ? (const void*)b3 : (const void*)b2;
    zero16(acc0); zero16(acc1);
    #pragma unroll 2
    for (int ks = 0; ks < 16; ++ks){
      short8 A0, A1, A2;
      splitAT(&sF[nn*STRF + ks*16 + hi*8], A0, A1, A2);
      const USHORT* bp = Wp + (((ks*2 + hi)*256) + tb0 + nn)*8;
      short8 B00 = *(const short8*)bp;
      short8 B01 = *(const short8*)(bp + 256);
      acc0 = mfma32(A0, B00, acc0); acc1 = mfma32(A0, B01, acc1);
      acc0 = mfma32(A1, B00, acc0); acc1 = mfma32(A1, B01, acc1);
      acc0 = mfma32(A2, B00, acc0); acc1 = mfma32(A2, B01, acc1);
      if (f32m){
        short8 B10 = *(const short8*)(bp + PS_W2);
        short8 B11 = *(const short8*)(bp + PS_W2 + 256);
        short8 B20 = *(const short8*)(bp + 2*PS_W2);
        short8 B21 = *(const short8*)(bp + 2*PS_W2 + 256);
        acc0 = mfma32(A0, B10, acc0); acc1 = mfma32(A0, B11, acc1);
        acc0 = mfma32(A1, B10, acc0); acc1 = mfma32(A1, B11, acc1);
        acc0 = mfma32(A0, B20, acc0); acc1 = mfma32(A0, B21, acc1);
      }
    }
    __syncthreads();
    {
      float bs0 = loadF(bb, tb0 + nn, f32m);
      float bs1 = loadF(bb, tb0 + 32 + nn, f32m);
      #pragma unroll
      for (int reg = 0; reg < 16; ++reg){
        int r = (reg&3) + 8*(reg>>2) + 4*hi;
        sF[r*STRF + tb0 + nn]      = fmaxf(acc0[reg] + bs0, 0.f);
        sF[r*STRF + tb0 + 32 + nn] = fmaxf(acc1[reg] + bs1, 0.f);
      }
    }
    __syncthreads();
  }

  // ---- mu: N=64, 16x16x32 (wave w -> 16-col tile), dual row-groups, no relu
  {
    f32x4 am0, am1;
    #pragma unroll
    for (int i = 0; i < 4; ++i){ am0[i] = 0.f; am1[i] = 0.f; }
    #pragma unroll 2
    for (int kc = 0; kc < 8; ++kc){
      short8 A0a, A1a, A2a, A0b, A1b, A2b;
      splitAT(&sF[l16*STRF + kc*32 + quad*8],        A0a, A1a, A2a);
      splitAT(&sF[(l16 + 16)*STRF + kc*32 + quad*8], A0b, A1b, A2b);
      const USHORT* bp = Wmup + ((kc*4 + quad)*64 + w*16 + l16)*8;
      short8 Bm0 = *(const short8*)bp;
      am0 = mfma16(A0a, Bm0, am0); am1 = mfma16(A0b, Bm0, am1);
      am0 = mfma16(A1a, Bm0, am0); am1 = mfma16(A1b, Bm0, am1);
      am0 = mfma16(A2a, Bm0, am0); am1 = mfma16(A2b, Bm0, am1);
      if (f32m){
        short8 Bm1 = *(const short8*)(bp + PS_MU);
        am0 = mfma16(A0a, Bm1, am0); am1 = mfma16(A0b, Bm1, am1);
        am0 = mfma16(A1a, Bm1, am0); am1 = mfma16(A1b, Bm1, am1);
        short8 Bm2 = *(const short8*)(bp + 2*PS_MU);
        am0 = mfma16(A0a, Bm2, am0); am1 = mfma16(A0b, Bm2, am1);
      }
    }
    __syncthreads();
    float bm = loadF(bmu, w*16 + l16, f32m);
    #pragma unroll
    for (int r = 0; r < 4; ++r){
      sF[(quad*4 + r)*STRF + w*16 + l16]        = am0[r] + bm;
      sF[(quad*4 + r + 16)*STRF + w*16 + l16]   = am1[r] + bm;
    }
    __syncthreads();
  }

  // ---- VQ: argmin_k(||e_k||^2 - 2 mu.e_k); wave w scans codes [w*256, +256)
  {
    short8 MA0[4], MA1[4], MA2[4];
    #pragma unroll
    for (int ks = 0; ks < 4; ++ks)
      splitAT(&sF[nn*STRF + ks*16 + hi*8], MA0[ks], MA1[ks], MA2[ks]);
    float minv[16]; int minc[16];
    #pragma unroll
    for (int i = 0; i < 16; ++i){ minv[i] = 3.4e38f; minc[i] = 0; }
    for (int tt = 0; tt < 8; ++tt){              // 32 codes per tile
      int cb = w*256 + tt*32;
      f32x16 ad; zero16(ad);
      #pragma unroll
      for (int ks = 0; ks < 4; ++ks){
        const USHORT* bp = Wep + (((ks*2 + hi)*1024) + cb + nn)*8;
        short8 B0 = *(const short8*)bp;
        ad = mfma32(MA0[ks], B0, ad);
        ad = mfma32(MA1[ks], B0, ad);
        ad = mfma32(MA2[ks], B0, ad);
        if (f32m){
          short8 B1 = *(const short8*)(bp + PS_WE);
          ad = mfma32(MA0[ks], B1, ad);
          ad = mfma32(MA1[ks], B1, ad);
          short8 B2 = *(const short8*)(bp + 2*PS_WE);
          ad = mfma32(MA0[ks], B2, ad);
        }
      }
      int code = cb + nn;
      float en = enorm[code];
      #pragma unroll
      for (int reg = 0; reg < 16; ++reg){
        float d = en - 2.f*ad[reg];
        if (d < minv[reg] || (d == minv[reg] && code < minc[reg])){ minv[reg] = d; minc[reg] = code; }
      }
    }
    // reduce across the 32 code-lanes of each half (rows differ by half!)
    #pragma unroll
    for (int off = 16; off >= 1; off >>= 1){
      #pragma unroll
      for (int reg = 0; reg < 16; ++reg){
        float ov = __shfl_xor(minv[reg], off, 64);
        int   oc = __shfl_xor(minc[reg], off, 64);
        if (ov < minv[reg] || (ov == minv[reg] && oc < minc[reg])){ minv[reg] = ov; minc[reg] = oc; }
      }
    }
    if (nn == 0){
      #pragma unroll
      for (int reg = 0; reg < 16; ++reg){
        int r = (reg&3) + 8*(reg>>2) + 4*hi;
        rMin[w][r]  = minv[reg];
        rCode[w][r] = minc[reg];
      }
    }
  }
  __syncthreads();

  // combine the 4 wave-quarters (ascending -> lowest-index tie-break), histogram
  if (tid < 32){
    float bv = rMin[0][tid]; int bc = rCode[0][tid];
    #pragma unroll
    for (int ww = 1; ww < 4; ++ww){
      float v = rMin[ww][tid]; int cd = rCode[ww][tid];
      if (v < bv || (v == bv && cd < bc)){ bv = v; bc = cd; }
    }
    rCode[0][tid] = bc;                      // codes[]
    atomicAdd(&counts[bc], 1u);
  }
  __syncthreads();

  // ---- loss: thread t -> (row = t>>3, dims (t&7)*8 ..+8)
  {
    int lrow = tid >> 3;
    int j0 = (tid & 7) * 8;
    int code = rCode[0][lrow];
    float lp = 0.f;
    #pragma unroll
    for (int jj = 0; jj < 8; ++jj){
      int l = j0 + jj;
      float qv = loadF(embed, (long)l*1024 + code, f32m);
      float d = qv - sF[lrow*STRF + l];
      lp += d*d;
    }
    #pragma unroll
    for (int off = 32; off >= 1; off >>= 1) lp += __shfl_xor(lp, off, 64);
    if (lane == 0) rMin[0][w] = lp;
  }
  __syncthreads();                            // all sF reads done; sA may be written
  if (tid == 0)
    atomicAdd(loss_sum, rMin[0][0] + rMin[0][1] + rMin[0][2] + rMin[0][3]);

  // ================= decoder (bf16 1-plane) =================
  // stage s2 = [q | c | 0pad], width 360 (331 used)
  {
    // q: from Wep plane0 ( == f2b(embed) ), 8 contiguous short8 per row
    int rr = tid >> 3, jg = tid & 7;
    int code = rCode[0][rr];
    short8 qv = *(const short8*)(Wep + ((long)jg*1024 + code)*8);
    *(short8*)&sA[rr*STRA + jg*8] = qv;
  }
  for (int rr = w*8; rr < w*8 + 8; ++rr){
    long grow = gbase + rr;
    for (int col = 64 + lane; col < 360; col += 64){
      float v = (col < 331) ? loadF(cc, grow*267 + (col - 64), f32m) : 0.f;
      sA[rr*STRA + col] = f2b(v);
    }
  }
  __syncthreads();

  // ---- fc4: K=352 (22 k-steps) : sA -> sB
  zero16(acc0); zero16(acc1);
  #pragma unroll 2
  for (int ks = 0; ks < 22; ++ks){
    short8 A = *(const short8*)&sA[nn*STRA + ks*16 + hi*8];
    const USHORT* bp = W4p + (((ks*2 + hi)*256) + tb0 + nn)*8;
    acc0 = mfma32(A, *(const short8*)bp,         acc0);
    acc1 = mfma32(A, *(const short8*)(bp + 256), acc1);
  }
  {
    float bs0 = loadF(b4, tb0 + nn, f32m);
    float bs1 = loadF(b4, tb0 + 32 + nn, f32m);
    #pragma unroll
    for (int reg = 0; reg < 16; ++reg){
      int r = (reg&3) + 8*(reg>>2) + 4*hi;
      sB[r*STRB + tb0 + nn]      = f2b(fmaxf(acc0[reg] + bs0, 0.f));
      sB[r*STRB + tb0 + 32 + nn] = f2b(fmaxf(acc1[reg] + bs1, 0.f));
    }
  }
  __syncthreads();

  // ---- fc5: sB -> sA (in-place-flip: barrier between read and write)
  zero16(acc0); zero16(acc1);
  #pragma unroll 4
  for (int ks = 0; ks < 16; ++ks){
    short8 A = *(const short8*)&sB[nn*STRB + ks*16 + hi*8];
    const USHORT* bp = W5p + (((ks*2 + hi)*256) + tb0 + nn)*8;
    acc0 = mfma32(A, *(const short8*)bp,         acc0);
    acc1 = mfma32(A, *(const short8*)(bp + 256), acc1);
  }
  __syncthreads();
  {
    float bs0 = loadF(b5, tb0 + nn, f32m);
    float bs1 = loadF(b5, tb0 + 32 + nn, f32m);
    #pragma unroll
    for (int reg = 0; reg < 16; ++reg){
      int r = (reg&3) + 8*(reg>>2) + 4*hi;
      sA[r*STRA + tb0 + nn]      = f2b(fmaxf(acc0[reg] + bs0, 0.f));
      sA[r*STRA + tb0 + 32 + nn] = f2b(fmaxf(acc1[reg] + bs1, 0.f));
    }
  }
  __syncthreads();

  // ---- fc6: sA -> sB
  zero16(acc0); zero16(acc1);
  #pragma unroll 4
  for (int ks = 0; ks < 16; ++ks){
    short8 A = *(const short8*)&sA[nn*STRA + ks*16 + hi*8];
    const USHORT* bp = W6p + (((ks*2 + hi)*256) + tb0 + nn)*8;
    acc0 = mfma32(A, *(const short8*)bp,         acc0);
    acc1 = mfma32(A, *(const short8*)(bp + 256), acc1);
  }
  __syncthreads();
  {
    float bs0 = loadF(b6, tb0 + nn, f32m);
    float bs1 = loadF(b6, tb0 + 32 + nn, f32m);
    #pragma unroll
    for (int reg = 0; reg < 16; ++reg){
      int r = (reg&3) + 8*(reg>>2) + 4*hi;
      sB[r*STRB + tb0 + nn]      = f2b(fmaxf(acc0[reg] + bs0, 0.f));
      sB[r*STRB + tb0 + 32 + nn] = f2b(fmaxf(acc1[reg] + bs1, 0.f));
    }
  }
  __syncthreads();

  // ---- out: N=288 padded (267 real); waves 0-2: 2 tiles, wave 3: 3 tiles
  {
    f32x16 acco0, acco1, acco2;
    zero16(acco0); zero16(acco1); zero16(acco2);
    #pragma unroll 2
    for (int ks = 0; ks < 16; ++ks){
      short8 A = *(const short8*)&sB[nn*STRB + ks*16 + hi*8];
      const USHORT* bp = Wop + (((ks*2 + hi)*288) + w*64 + nn)*8;
      acco0 = mfma32(A, *(const short8*)bp,         acco0);
      acco1 = mfma32(A, *(const short8*)(bp + 256), acco1);
      if (w == 3) acco2 = mfma32(A, *(const short8*)(bp + 512), acco2);
    }
    int ntiles = (w == 3) ? 3 : 2;
    #pragma unroll
    for (int t = 0; t < 3; ++t){
      if (t < ntiles){
        int col = w*64 + t*32 + nn;
        if (col < 267){
          float bias = loadF(bo, col, f32m);
          f32x16& a = (t == 0) ? acco0 : (t == 1) ? acco1 : acco2;
          #pragma unroll
          for (int reg = 0; reg < 16; ++reg){
            int r = (reg&3) + 8*(reg>>2) + 4*hi;
            long oi = (gbase + r)*267 + col;
            float val = a[reg] + bias;
            if (f32m) ((float*)out)[oi] = val;
            else      ((USHORT*)out)[oi] = f2b(val);
          }
        }
      }
    }
  }
}

// ---------------------------------------------------------------------------
// finalize: loss mean + perplexity from histogram
// ---------------------------------------------------------------------------
__global__ void vq_fin_kernel(const void* __restrict__ x,
                              const UINT* __restrict__ counts,
                              const float* __restrict__ loss_sum,
                              void* __restrict__ out)
{
  __shared__ float red[4];
  int f32m = detect_f32(x);
  int tid = threadIdx.x;
  float Hl = 0.f;
  for (int k = tid; k < 1024; k += 256){
    float p = (float)counts[k] * (1.f/65536.f);
    Hl -= p * logf(p + 1e-10f);
  }
  #pragma unroll
  for (int off = 32; off >= 1; off >>= 1) Hl += __shfl_xor(Hl, off, 64);
  if ((tid & 63) == 0) red[tid >> 6] = Hl;
  __syncthreads();
  if (tid == 0){
    float H = red[0] + red[1] + red[2] + red[3];
    float loss = *loss_sum * (1.f/4194304.f);   // /(B*L)
    float ppx  = expf(H);
    size_t base = (size_t)65536*267;
    if (f32m){
      ((float*)out)[base]     = loss;
      ((float*)out)[base + 1] = ppx;
    } else {
      ((USHORT*)out)[base]     = f2b(loss);
      ((USHORT*)out)[base + 1] = f2b(ppx);
    }
  }
}

// ---------------------------------------------------------------------------
extern "C" void kernel_launch(void* const* d_in, const int* in_sizes, int n_in,
                              void* d_out, int out_size, void* d_ws, size_t ws_size,
                              hipStream_t stream)
{
  const void* x    = d_in[0];
  const void* c    = d_in[1];
  const void* fc1w = d_in[2];
  const void* fc1b = d_in[3];
  const void* fc2w = d_in[4];
  const void* fc2b = d_in[5];
  const void* fc3w = d_in[6];
  const void* fc3b = d_in[7];
  const void* muw  = d_in[8];
  const void* mub  = d_in[9];
  const void* fc4w = d_in[10];
  const void* fc4b = d_in[11];
  const void* fc5w = d_in[12];
  const void* fc5b = d_in[13];
  const void* fc6w = d_in[14];
  const void* fc6b = d_in[15];
  const void* outw = d_in[16];
  const void* outb = d_in[17];
  const void* embed= d_in[18];

  char* ws = (char*)d_ws;
  UINT*   counts = (UINT*)  (ws + OFF_COUNTS);
  float*  lsum   = (float*) (ws + OFF_LOSS);
  float*  enorm  = (float*) (ws + OFF_ENORM);
  USHORT* W1p = (USHORT*)(ws + OFF_W1);
  USHORT* W2p = (USHORT*)(ws + OFF_W2);
  USHORT* W3p = (USHORT*)(ws + OFF_W3);
  USHORT* Wmup= (USHORT*)(ws + OFF_WMU);
  USHORT* Wep = (USHORT*)(ws + OFF_WE);
  USHORT* W4p = (USHORT*)(ws + OFF_W4);
  USHORT* W5p = (USHORT*)(ws + OFF_W5);
  USHORT* W6p = (USHORT*)(ws + OFF_W6);
  USHORT* Wop = (USHORT*)(ws + OFF_WO);

  // 2 elements/thread -> 272 blocks covers the largest table (544*256 elems)
  dim3 pgrid(272, 11, 1);
  vq_prep_kernel<<<pgrid, 256, 0, stream>>>(
      x, fc1w, fc2w, fc3w, muw, fc4w, fc5w, fc6w, outw, embed,
      W1p, W2p, W3p, Wmup, Wep, W4p, W5p, W6p, Wop, enorm, counts, lsum);

  vq_main_kernel<<<2048, 256, 0, stream>>>(
      x, c, fc1b, fc2b, fc3b, mub, fc4b, fc5b, fc6b, outb, embed,
      W1p, W2p, W3p, Wmup, Wep, enorm,
      W4p, W5p, W6p, Wop, counts, lsum, d_out);

  vq_fin_kernel<<<1, 256, 0, stream>>>(x, counts, lsum, d_out);
}

// Round 9
// 1145.293 us; speedup vs baseline: 1.1559x; 1.0133x over previous
//
#include <hip/hip_runtime.h>

// ---------------------------------------------------------------------------
// PoseVQVAE fused forward. DUAL-MODE storage dtype (f32 vs bf16) sniffed
// on-device. Math core: bf16 MFMA 32x32x16 (main path), 16x16x32 (mu),
// encoder 3-plane trunc-splits (split on READ from f32 LDS acts),
// decoder 1-plane bf16.
// Round 9 = round-8 (passing, 1030us main) +
//  (1) VQ: two INDEPENDENT tiles interleaved (own accumulators, R2-exact
//      per-tile FP order + ascending min-update order -> bit-identical
//      argmin by construction). Halves the 24-deep VQ MFMA dep chain.
//  (2) decoder fc4/5/6/out: even/odd K-split into 4 accumulator chains,
//      merged with one f32 add (no argmin downstream; recon margin 2.9x).
// fc1 software pipeline & B ping-pong (R5/R6) remain quarantined.
// ---------------------------------------------------------------------------

using short8 = __attribute__((ext_vector_type(8))) short;
using f32x4  = __attribute__((ext_vector_type(4))) float;
using f32x16 = __attribute__((ext_vector_type(16))) float;

#define USHORT unsigned short
#define UINT   unsigned int

// plane sizes in ushorts
#define PS_W1  139264   // 544*256
#define PS_W2  65536    // 256*256
#define PS_MU  16384    // 256*64
#define PS_WE  65536    // 64*1024

// LDS geometry
#define STRF 260        // f32 activation stride
#define STRX 276        // fc1 staging stride (f32)
#define STRA 360        // dec sA stride (ushort)
#define STRB 264        // dec sB stride (ushort)

// ---- ws layout (bytes), 64B-aligned ----
static const size_t OFF_COUNTS = 262144;    // 1024*4
static const size_t OFF_LOSS   = 266240;    // 4 (+pad)
static const size_t OFF_ENORM  = 266304;    // 1024*4
static const size_t OFF_W1     = 270400;    // 3 planes * 139264 * 2 = 835584
static const size_t OFF_W2     = 1105984;   // 3*65536*2 = 393216
static const size_t OFF_W3     = 1499200;   // 393216
static const size_t OFF_WMU    = 1892416;   // 3*16384*2 = 98304
static const size_t OFF_WE     = 1990720;   // 3*65536*2 = 393216
static const size_t OFF_W4     = 2383936;   // 352*256*2 = 180224
static const size_t OFF_W5     = 2564160;   // 131072
static const size_t OFF_W6     = 2695232;   // 131072
static const size_t OFF_WO     = 2826304;   // 256*288*2 = 147456 -> end ~2.98MB

__device__ __forceinline__ float b2f(USHORT u){
  return __uint_as_float(((UINT)u) << 16);
}
__device__ __forceinline__ USHORT f2b(float f){            // RNE f32->bf16
  UINT u = __float_as_uint(f);
  u += 0x7fffu + ((u >> 16) & 1u);
  return (USHORT)(u >> 16);
}
__device__ __forceinline__ float loadF(const void* p, long i, int f32m){
  if (f32m) return ((const float*)p)[i];
  return b2f(((const USHORT*)p)[i]);
}
// RNE 3-plane split (prep / weights; validated numerics)
__device__ __forceinline__ void split3(float h, USHORT& a, USHORT& b, USHORT& c){
  a = f2b(h); float r = h - b2f(a);
  b = f2b(r); r -= b2f(b);
  c = f2b(r);
}
// truncation 3-plane split (hot path): a+b+c == h to ~2^-24, 7-9 VALU ops
__device__ __forceinline__ void splitT(float h, USHORT& a, USHORT& b, USHORT& c){
  UINT u = __float_as_uint(h);
  a = (USHORT)(u >> 16);
  float r = h - __uint_as_float(u & 0xffff0000u);
  UINT v = __float_as_uint(r);
  b = (USHORT)(v >> 16);
  float r2 = r - __uint_as_float(v & 0xffff0000u);
  c = f2b(r2);
}
__device__ __forceinline__ f32x4 mfma16(short8 a, short8 b, f32x4 c){
  return __builtin_amdgcn_mfma_f32_16x16x32_bf16(a, b, c, 0, 0, 0);
}
__device__ __forceinline__ f32x16 mfma32(short8 a, short8 b, f32x16 c){
  return __builtin_amdgcn_mfma_f32_32x32x16_bf16(a, b, c, 0, 0, 0);
}
__device__ __forceinline__ void zero16(f32x16& v){
  #pragma unroll
  for (int i = 0; i < 16; ++i) v[i] = 0.f;
}
// build 3 A-planes from 8 consecutive f32 in LDS (trunc split)
__device__ __forceinline__ void splitAT(const float* p, short8& A0, short8& A1, short8& A2){
  #pragma unroll
  for (int j = 0; j < 8; ++j){
    USHORT t0, t1, t2; splitT(p[j], t0, t1, t2);
    A0[j] = (short)t0; A1[j] = (short)t1; A2[j] = (short)t2;
  }
}
// dtype sniff (wave-uniform): bf16 storage -> low u16 exponent in [117,130]
__device__ __forceinline__ int detect_f32(const void* x){
  UINT u = ((const UINT*)x)[threadIdx.x & 63];
  int e = (int)((u >> 7) & 0xFFu);
  unsigned long long m = __ballot(e >= 117 && e <= 130);
  return __popcll(m) < 32;
}

// ---------------------------------------------------------------------------
// prep: repack weights into [K/8][N][8] bf16 planes; enorm; zero accums.
// ---------------------------------------------------------------------------
__device__ __forceinline__ void fillW(USHORT* dst, const void* src,
                                      int Kpad, int N, int Ksrc, int Nsrc,
                                      int srcStride, bool kmajor, int t,
                                      int f32m, int planes)
{
  int total = Kpad * N;
  if (t >= total) return;
  int j = t & 7, rest = t >> 3;
  int n = rest % N, kg = rest / N;
  int k = kg*8 + j;
  float v = 0.f;
  if (k < Ksrc && n < Nsrc)
    v = loadF(src, kmajor ? (long)k*srcStride + n : (long)n*srcStride + k, f32m);
  if (planes == 1){ dst[t] = f2b(v); return; }
  USHORT t0, t1, t2; split3(v, t0, t1, t2);
  dst[t] = t0; dst[total + t] = t1; dst[2*total + t] = t2;
}

__global__ void vq_prep_kernel(
    const void* xx,
    const void* fc1w, const void* fc2w, const void* fc3w,
    const void* muw,  const void* fc4w, const void* fc5w,
    const void* fc6w, const void* outw, const void* embed,
    USHORT* W1p, USHORT* W2p, USHORT* W3p, USHORT* Wmup, USHORT* Wep,
    USHORT* W4p, USHORT* W5p, USHORT* W6p, USHORT* Wop,
    float* enorm, UINT* counts, float* loss_sum)
{
  int f32m = detect_f32(xx);
  int t0 = (blockIdx.x * 256 + threadIdx.x) * 2;
  #pragma unroll
  for (int e = 0; e < 2; ++e){
    int t = t0 + e;
    switch (blockIdx.y){
      case 0: fillW(W1p,  fc1w, 544, 256, 534, 256, 534, false, t, f32m, 3); break;
      case 1: fillW(W2p,  fc2w, 256, 256, 256, 256, 256, false, t, f32m, 3); break;
      case 2: fillW(W3p,  fc3w, 256, 256, 256, 256, 256, false, t, f32m, 3); break;
      case 3: fillW(Wmup, muw,  256,  64, 256,  64, 256, false, t, f32m, 3); break;
      case 4: fillW(Wep,  embed, 64, 1024, 64, 1024, 1024, true, t, f32m, 3); break;
      case 5: fillW(W4p,  fc4w, 352, 256, 331, 256, 331, false, t, f32m, 1); break;
      case 6: fillW(W5p,  fc5w, 256, 256, 256, 256, 256, false, t, f32m, 1); break;
      case 7: fillW(W6p,  fc6w, 256, 256, 256, 256, 256, false, t, f32m, 1); break;
      case 8: fillW(Wop,  outw, 256, 288, 256, 267, 256, false, t, f32m, 1); break;
      case 9:
        if (t < 1024){
          double s = 0.0;
          for (int l = 0; l < 64; ++l){
            double ev = (double)loadF(embed, (long)l*1024 + t, f32m); s += ev*ev;
          }
          enorm[t] = (float)s;
        }
        break;
      case 10:
        if (t < 1024) counts[t] = 0u;
        if (t == 1024) *loss_sum = 0.f;
        break;
    }
  }
}

// ---------------------------------------------------------------------------
// fused main: 32 rows/block, 256 threads (4 waves).
// Wave w owns ALL 32 rows x 64-col slice (tb0 = w*64) -> B read once/block.
// MFMA 32x32x16: A row = lane&31, k = (lane>>5)*8 + j;
//                C/D: col = lane&31, row = (reg&3) + 8*(reg>>2) + 4*(lane>>5)
// ---------------------------------------------------------------------------
__global__ __launch_bounds__(256, 4) void vq_main_kernel(
    const void* __restrict__ x,  const void* __restrict__ cc,
    const void* __restrict__ b1, const void* __restrict__ b2,
    const void* __restrict__ b3, const void* __restrict__ bmu,
    const void* __restrict__ b4, const void* __restrict__ b5,
    const void* __restrict__ b6, const void* __restrict__ bo,
    const void* __restrict__ embed,
    const USHORT* __restrict__ W1p, const USHORT* __restrict__ W2p,
    const USHORT* __restrict__ W3p, const USHORT* __restrict__ Wmup,
    const USHORT* __restrict__ Wep, const float* __restrict__ enorm,
    const USHORT* __restrict__ W4p, const USHORT* __restrict__ W5p,
    const USHORT* __restrict__ W6p, const USHORT* __restrict__ Wop,
    UINT* __restrict__ counts, float* __restrict__ loss_sum,
    void* __restrict__ out)
{
  // union buffer U (39936B), time-multiplexed:
  //   fc1:       sX staging [32][276] f32 (35328B)
  //   fc2..VQ:   sF acts    [32][260] f32 (33280B)
  //   decoder:   sA [32][360] bf16 (23040B) + sB [32][264] bf16 (16896B)
  __shared__ __align__(16) char U[39936];
  __shared__ float rMin[4][32];
  __shared__ int   rCode[4][32];        // rCode[0] becomes the codes[] after combine
  float*  sF = (float*)U;
  USHORT* sA = (USHORT*)U;
  USHORT* sB = (USHORT*)(U + 23040);

  const int f32m = detect_f32(x);
  const int tid  = threadIdx.x;
  const int w    = tid >> 6;
  const int lane = tid & 63;
  const int hi   = lane >> 5;
  const int nn   = lane & 31;
  const int quad = lane >> 4;
  const int l16  = lane & 15;
  const int tb0  = w * 64;                   // this wave's 64-col slice
  const long gbase = (long)blockIdx.x * 32;
  const long gr    = gbase + nn;             // global row for A fragments

  f32x16 acc0, acc1;
  zero16(acc0); zero16(acc1);

  // ================= encoder =================
  // ---- fc1: K=544 (34 k-steps of 16); A staged via LDS (f32 mode)
  if (f32m){
    float* sX = (float*)U;                   // dead before sF is first written
    #pragma unroll
    for (int ch = 0; ch < 2; ++ch){
      const int cb0 = ch * 272;
      // stage: wave w rows w*8..+7, coalesced 64-lane bursts, independent loads
      for (int rr = w*8; rr < w*8 + 8; ++rr){
        const float* xr = (const float*)x  + (gbase + rr)*267;
        const float* cr = (const float*)cc + (gbase + rr)*267;
        for (int c = lane; c < 272; c += 64){
          int gc = cb0 + c;
          float v = 0.f;
          if (gc < 267)      v = xr[gc];
          else if (gc < 534) v = cr[gc - 267];
          sX[rr*STRX + c] = v;
        }
      }
      __syncthreads();
      const int ksBeg = ch ? 17 : 0;
      const int ksEnd = ch ? 34 : 17;
      for (int ks = ksBeg; ks < ksEnd; ++ks){
        short8 A0, A1, A2;
        splitAT(&sX[nn*STRX + (ks*16 - cb0) + hi*8], A0, A1, A2);
        const USHORT* bp = W1p + (((ks*2 + hi)*256) + tb0 + nn)*8;
        short8 B00 = *(const short8*)bp;
        short8 B01 = *(const short8*)(bp + 256);
        short8 B10 = *(const short8*)(bp + PS_W1);
        short8 B11 = *(const short8*)(bp + PS_W1 + 256);
        short8 B20 = *(const short8*)(bp + 2*PS_W1);
        short8 B21 = *(const short8*)(bp + 2*PS_W1 + 256);
        acc0 = mfma32(A0, B00, acc0); acc1 = mfma32(A0, B01, acc1);
        acc0 = mfma32(A1, B00, acc0); acc1 = mfma32(A1, B01, acc1);
        acc0 = mfma32(A2, B00, acc0); acc1 = mfma32(A2, B01, acc1);
        acc0 = mfma32(A0, B10, acc0); acc1 = mfma32(A0, B11, acc1);
        acc0 = mfma32(A1, B10, acc0); acc1 = mfma32(A1, B11, acc1);
        acc0 = mfma32(A0, B20, acc0); acc1 = mfma32(A0, B21, acc1);
      }
      __syncthreads();   // all sX reads done before restage / sF write
    }
  } else {
    for (int ks = 0; ks < 34; ++ks){
      short8 A0;
      #pragma unroll
      for (int j = 0; j < 8; ++j){
        int col = ks*16 + hi*8 + j;
        USHORT u = 0;
        if (col < 267)      u = ((const USHORT*)x)[gr*267 + col];
        else if (col < 534) u = ((const USHORT*)cc)[gr*267 + (col - 267)];
        A0[j] = (short)u;
      }
      const USHORT* bp = W1p + (((ks*2 + hi)*256) + tb0 + nn)*8;
      short8 B00 = *(const short8*)bp;
      short8 B01 = *(const short8*)(bp + 256);
      acc0 = mfma32(A0, B00, acc0); acc1 = mfma32(A0, B01, acc1);
    }
  }
  {
    float bs0 = loadF(b1, tb0 + nn, f32m);
    float bs1 = loadF(b1, tb0 + 32 + nn, f32m);
    #pragma unroll
    for (int reg = 0; reg < 16; ++reg){
      int r = (reg&3) + 8*(reg>>2) + 4*hi;
      sF[r*STRF + tb0 + nn]      = fmaxf(acc0[reg] + bs0, 0.f);
      sF[r*STRF + tb0 + 32 + nn] = fmaxf(acc1[reg] + bs1, 0.f);
    }
  }
  __syncthreads();

  // ---- fc2, fc3: in-place f32 LDS, trunc-split-on-read, K=256 (16 k-steps)
  for (int layer = 0; layer < 2; ++layer){
    const USHORT* Wp = layer ? W3p : W2p;
    const void*   bb = layer ? (const void*)b3 : (const void*)b2;
    zero16(acc0); zero16(acc1);
    #pragma unroll 2
    for (int ks = 0; ks < 16; ++ks){
      short8 A0, A1, A2;
      splitAT(&sF[nn*STRF + ks*16 + hi*8], A0, A1, A2);
      const USHORT* bp = Wp + (((ks*2 + hi)*256) + tb0 + nn)*8;
      short8 B00 = *(const short8*)bp;
      short8 B01 = *(const short8*)(bp + 256);
      acc0 = mfma32(A0, B00, acc0); acc1 = mfma32(A0, B01, acc1);
      acc0 = mfma32(A1, B00, acc0); acc1 = mfma32(A1, B01, acc1);
      acc0 = mfma32(A2, B00, acc0); acc1 = mfma32(A2, B01, acc1);
      if (f32m){
        short8 B10 = *(const short8*)(bp + PS_W2);
        short8 B11 = *(const short8*)(bp + PS_W2 + 256);
        short8 B20 = *(const short8*)(bp + 2*PS_W2);
        short8 B21 = *(const short8*)(bp + 2*PS_W2 + 256);
        acc0 = mfma32(A0, B10, acc0); acc1 = mfma32(A0, B11, acc1);
        acc0 = mfma32(A1, B10, acc0); acc1 = mfma32(A1, B11, acc1);
        acc0 = mfma32(A0, B20, acc0); acc1 = mfma32(A0, B21, acc1);
      }
    }
    __syncthreads();
    {
      float bs0 = loadF(bb, tb0 + nn, f32m);
      float bs1 = loadF(bb, tb0 + 32 + nn, f32m);
      #pragma unroll
      for (int reg = 0; reg < 16; ++reg){
        int r = (reg&3) + 8*(reg>>2) + 4*hi;
        sF[r*STRF + tb0 + nn]      = fmaxf(acc0[reg] + bs0, 0.f);
        sF[r*STRF + tb0 + 32 + nn] = fmaxf(acc1[reg] + bs1, 0.f);
      }
    }
    __syncthreads();
  }

  // ---- mu: N=64, 16x16x32 (wave w -> 16-col tile), dual row-groups, no relu
  {
    f32x4 am0, am1;
    #pragma unroll
    for (int i = 0; i < 4; ++i){ am0[i] = 0.f; am1[i] = 0.f; }
    #pragma unroll 2
    for (int kc = 0; kc < 8; ++kc){
      short8 A0a, A1a, A2a, A0b, A1b, A2b;
      splitAT(&sF[l16*STRF + kc*32 + quad*8],        A0a, A1a, A2a);
      splitAT(&sF[(l16 + 16)*STRF + kc*32 + quad*8], A0b, A1b, A2b);
      const USHORT* bp = Wmup + ((kc*4 + quad)*64 + w*16 + l16)*8;
      short8 Bm0 = *(const short8*)bp;
      am0 = mfma16(A0a, Bm0, am0); am1 = mfma16(A0b, Bm0, am1);
      am0 = mfma16(A1a, Bm0, am0); am1 = mfma16(A1b, Bm0, am1);
      am0 = mfma16(A2a, Bm0, am0); am1 = mfma16(A2b, Bm0, am1);
      if (f32m){
        short8 Bm1 = *(const short8*)(bp + PS_MU);
        am0 = mfma16(A0a, Bm1, am0); am1 = mfma16(A0b, Bm1, am1);
        am0 = mfma16(A1a, Bm1, am0); am1 = mfma16(A1b, Bm1, am1);
        short8 Bm2 = *(const short8*)(bp + 2*PS_MU);
        am0 = mfma16(A0a, Bm2, am0); am1 = mfma16(A0b, Bm2, am1);
      }
    }
    __syncthreads();
    float bm = loadF(bmu, w*16 + l16, f32m);
    #pragma unroll
    for (int r = 0; r < 4; ++r){
      sF[(quad*4 + r)*STRF + w*16 + l16]        = am0[r] + bm;
      sF[(quad*4 + r + 16)*STRF + w*16 + l16]   = am1[r] + bm;
    }
    __syncthreads();
  }

  // ---- VQ: argmin_k(||e_k||^2 - 2 mu.e_k); wave w scans codes [w*256, +256)
  // two INDEPENDENT tiles interleaved: each tile keeps R2's exact per-tile
  // FP accumulation order; min updates tileA then tileB = ascending code
  // order -> bit-identical (minv,minc) to the sequential version.
  {
    short8 MA0[4], MA1[4], MA2[4];
    #pragma unroll
    for (int ks = 0; ks < 4; ++ks)
      splitAT(&sF[nn*STRF + ks*16 + hi*8], MA0[ks], MA1[ks], MA2[ks]);
    float minv[16]; int minc[16];
    #pragma unroll
    for (int i = 0; i < 16; ++i){ minv[i] = 3.4e38f; minc[i] = 0; }
    for (int tp = 0; tp < 4; ++tp){              // 2 tiles x 32 codes per iter
      int cbA = w*256 + tp*64;
      int cbB = cbA + 32;
      f32x16 adA, adB; zero16(adA); zero16(adB);
      #pragma unroll
      for (int ks = 0; ks < 4; ++ks){
        const USHORT* bpA = Wep + (((ks*2 + hi)*1024) + cbA + nn)*8;
        const USHORT* bpB = Wep + (((ks*2 + hi)*1024) + cbB + nn)*8;
        short8 B0A = *(const short8*)bpA;
        short8 B0B = *(const short8*)bpB;
        adA = mfma32(MA0[ks], B0A, adA);  adB = mfma32(MA0[ks], B0B, adB);
        adA = mfma32(MA1[ks], B0A, adA);  adB = mfma32(MA1[ks], B0B, adB);
        adA = mfma32(MA2[ks], B0A, adA);  adB = mfma32(MA2[ks], B0B, adB);
        if (f32m){
          short8 B1A = *(const short8*)(bpA + PS_WE);
          short8 B1B = *(const short8*)(bpB + PS_WE);
          adA = mfma32(MA0[ks], B1A, adA);  adB = mfma32(MA0[ks], B1B, adB);
          adA = mfma32(MA1[ks], B1A, adA);  adB = mfma32(MA1[ks], B1B, adB);
          short8 B2A = *(const short8*)(bpA + 2*PS_WE);
          short8 B2B = *(const short8*)(bpB + 2*PS_WE);
          adA = mfma32(MA0[ks], B2A, adA);  adB = mfma32(MA0[ks], B2B, adB);
        }
      }
      int codeA = cbA + nn;
      float enA = enorm[codeA];
      #pragma unroll
      for (int reg = 0; reg < 16; ++reg){
        float d = enA - 2.f*adA[reg];
        if (d < minv[reg] || (d == minv[reg] && codeA < minc[reg])){ minv[reg] = d; minc[reg] = codeA; }
      }
      int codeB = cbB + nn;
      float enB = enorm[codeB];
      #pragma unroll
      for (int reg = 0; reg < 16; ++reg){
        float d = enB - 2.f*adB[reg];
        if (d < minv[reg] || (d == minv[reg] && codeB < minc[reg])){ minv[reg] = d; minc[reg] = codeB; }
      }
    }
    // reduce across the 32 code-lanes of each half (rows differ by half!)
    #pragma unroll
    for (int off = 16; off >= 1; off >>= 1){
      #pragma unroll
      for (int reg = 0; reg < 16; ++reg){
        float ov = __shfl_xor(minv[reg], off, 64);
        int   oc = __shfl_xor(minc[reg], off, 64);
        if (ov < minv[reg] || (ov == minv[reg] && oc < minc[reg])){ minv[reg] = ov; minc[reg] = oc; }
      }
    }
    if (nn == 0){
      #pragma unroll
      for (int reg = 0; reg < 16; ++reg){
        int r = (reg&3) + 8*(reg>>2) + 4*hi;
        rMin[w][r]  = minv[reg];
        rCode[w][r] = minc[reg];
      }
    }
  }
  __syncthreads();

  // combine the 4 wave-quarters (ascending -> lowest-index tie-break), histogram
  if (tid < 32){
    float bv = rMin[0][tid]; int bc = rCode[0][tid];
    #pragma unroll
    for (int ww = 1; ww < 4; ++ww){
      float v = rMin[ww][tid]; int cd = rCode[ww][tid];
      if (v < bv || (v == bv && cd < bc)){ bv = v; bc = cd; }
    }
    rCode[0][tid] = bc;                      // codes[]
    atomicAdd(&counts[bc], 1u);
  }
  __syncthreads();

  // ---- loss: thread t -> (row = t>>3, dims (t&7)*8 ..+8)
  {
    int lrow = tid >> 3;
    int j0 = (tid & 7) * 8;
    int code = rCode[0][lrow];
    float lp = 0.f;
    #pragma unroll
    for (int jj = 0; jj < 8; ++jj){
      int l = j0 + jj;
      float qv = loadF(embed, (long)l*1024 + code, f32m);
      float d = qv - sF[lrow*STRF + l];
      lp += d*d;
    }
    #pragma unroll
    for (int off = 32; off >= 1; off >>= 1) lp += __shfl_xor(lp, off, 64);
    if (lane == 0) rMin[0][w] = lp;
  }
  __syncthreads();                            // all sF reads done; sA may be written
  if (tid == 0)
    atomicAdd(loss_sum, rMin[0][0] + rMin[0][1] + rMin[0][2] + rMin[0][3]);

  // ================= decoder (bf16 1-plane, 4 accumulator chains) =========
  // stage s2 = [q | c | 0pad], width 360 (331 used)
  {
    // q: from Wep plane0 ( == f2b(embed) ), 8 contiguous short8 per row
    int rr = tid >> 3, jg = tid & 7;
    int code = rCode[0][rr];
    short8 qv = *(const short8*)(Wep + ((long)jg*1024 + code)*8);
    *(short8*)&sA[rr*STRA + jg*8] = qv;
  }
  for (int rr = w*8; rr < w*8 + 8; ++rr){
    long grow = gbase + rr;
    for (int col = 64 + lane; col < 360; col += 64){
      float v = (col < 331) ? loadF(cc, grow*267 + (col - 64), f32m) : 0.f;
      sA[rr*STRA + col] = f2b(v);
    }
  }
  __syncthreads();

  f32x16 acx, acy;   // odd-ks chains (merged into acc0/acc1 before epilogue)

  // ---- fc4: K=352 (22 k-steps, even/odd split) : sA -> sB
  zero16(acc0); zero16(acc1); zero16(acx); zero16(acy);
  #pragma unroll 2
  for (int ks = 0; ks < 22; ks += 2){
    short8 Ae = *(const short8*)&sA[nn*STRA + ks*16 + hi*8];
    const USHORT* bpe = W4p + (((ks*2 + hi)*256) + tb0 + nn)*8;
    acc0 = mfma32(Ae, *(const short8*)bpe,         acc0);
    acc1 = mfma32(Ae, *(const short8*)(bpe + 256), acc1);
    short8 Ao = *(const short8*)&sA[nn*STRA + (ks+1)*16 + hi*8];
    const USHORT* bpo = W4p + ((((ks+1)*2 + hi)*256) + tb0 + nn)*8;
    acx = mfma32(Ao, *(const short8*)bpo,         acx);
    acy = mfma32(Ao, *(const short8*)(bpo + 256), acy);
  }
  acc0 = acc0 + acx; acc1 = acc1 + acy;
  {
    float bs0 = loadF(b4, tb0 + nn, f32m);
    float bs1 = loadF(b4, tb0 + 32 + nn, f32m);
    #pragma unroll
    for (int reg = 0; reg < 16; ++reg){
      int r = (reg&3) + 8*(reg>>2) + 4*hi;
      sB[r*STRB + tb0 + nn]      = f2b(fmaxf(acc0[reg] + bs0, 0.f));
      sB[r*STRB + tb0 + 32 + nn] = f2b(fmaxf(acc1[reg] + bs1, 0.f));
    }
  }
  __syncthreads();

  // ---- fc5: sB -> sA (in-place-flip: barrier between read and write)
  zero16(acc0); zero16(acc1); zero16(acx); zero16(acy);
  #pragma unroll 2
  for (int ks = 0; ks < 16; ks += 2){
    short8 Ae = *(const short8*)&sB[nn*STRB + ks*16 + hi*8];
    const USHORT* bpe = W5p + (((ks*2 + hi)*256) + tb0 + nn)*8;
    acc0 = mfma32(Ae, *(const short8*)bpe,         acc0);
    acc1 = mfma32(Ae, *(const short8*)(bpe + 256), acc1);
    short8 Ao = *(const short8*)&sB[nn*STRB + (ks+1)*16 + hi*8];
    const USHORT* bpo = W5p + ((((ks+1)*2 + hi)*256) + tb0 + nn)*8;
    acx = mfma32(Ao, *(const short8*)bpo,         acx);
    acy = mfma32(Ao, *(const short8*)(bpo + 256), acy);
  }
  acc0 = acc0 + acx; acc1 = acc1 + acy;
  __syncthreads();
  {
    float bs0 = loadF(b5, tb0 + nn, f32m);
    float bs1 = loadF(b5, tb0 + 32 + nn, f32m);
    #pragma unroll
    for (int reg = 0; reg < 16; ++reg){
      int r = (reg&3) + 8*(reg>>2) + 4*hi;
      sA[r*STRA + tb0 + nn]      = f2b(fmaxf(acc0[reg] + bs0, 0.f));
      sA[r*STRA + tb0 + 32 + nn] = f2b(fmaxf(acc1[reg] + bs1, 0.f));
    }
  }
  __syncthreads();

  // ---- fc6: sA -> sB
  zero16(acc0); zero16(acc1); zero16(acx); zero16(acy);
  #pragma unroll 2
  for (int ks = 0; ks < 16; ks += 2){
    short8 Ae = *(const short8*)&sA[nn*STRA + ks*16 + hi*8];
    const USHORT* bpe = W6p + (((ks*2 + hi)*256) + tb0 + nn)*8;
    acc0 = mfma32(Ae, *(const short8*)bpe,         acc0);
    acc1 = mfma32(Ae, *(const short8*)(bpe + 256), acc1);
    short8 Ao = *(const short8*)&sA[nn*STRA + (ks+1)*16 + hi*8];
    const USHORT* bpo = W6p + ((((ks+1)*2 + hi)*256) + tb0 + nn)*8;
    acx = mfma32(Ao, *(const short8*)bpo,         acx);
    acy = mfma32(Ao, *(const short8*)(bpo + 256), acy);
  }
  acc0 = acc0 + acx; acc1 = acc1 + acy;
  __syncthreads();
  {
    float bs0 = loadF(b6, tb0 + nn, f32m);
    float bs1 = loadF(b6, tb0 + 32 + nn, f32m);
    #pragma unroll
    for (int reg = 0; reg < 16; ++reg){
      int r = (reg&3) + 8*(reg>>2) + 4*hi;
      sB[r*STRB + tb0 + nn]      = f2b(fmaxf(acc0[reg] + bs0, 0.f));
      sB[r*STRB + tb0 + 32 + nn] = f2b(fmaxf(acc1[reg] + bs1, 0.f));
    }
  }
  __syncthreads();

  // ---- out: N=288 padded (267 real); waves 0-2: 2 tiles, wave 3: 3 tiles
  {
    f32x16 acco0, acco1, acco2, acp0, acp1;
    zero16(acco0); zero16(acco1); zero16(acco2); zero16(acp0); zero16(acp1);
    #pragma unroll 2
    for (int ks = 0; ks < 16; ks += 2){
      short8 Ae = *(const short8*)&sB[nn*STRB + ks*16 + hi*8];
      const USHORT* bpe = Wop + (((ks*2 + hi)*288) + w*64 + nn)*8;
      acco0 = mfma32(Ae, *(const short8*)bpe,         acco0);
      acco1 = mfma32(Ae, *(const short8*)(bpe + 256), acco1);
      if (w == 3) acco2 = mfma32(Ae, *(const short8*)(bpe + 512), acco2);
      short8 Ao = *(const short8*)&sB[nn*STRB + (ks+1)*16 + hi*8];
      const USHORT* bpo = Wop + ((((ks+1)*2 + hi)*288) + w*64 + nn)*8;
      acp0 = mfma32(Ao, *(const short8*)bpo,         acp0);
      acp1 = mfma32(Ao, *(const short8*)(bpo + 256), acp1);
      if (w == 3) acco2 = mfma32(Ao, *(const short8*)(bpo + 512), acco2);
    }
    acco0 = acco0 + acp0; acco1 = acco1 + acp1;
    int ntiles = (w == 3) ? 3 : 2;
    #pragma unroll
    for (int t = 0; t < 3; ++t){
      if (t < ntiles){
        int col = w*64 + t*32 + nn;
        if (col < 267){
          float bias = loadF(bo, col, f32m);
          f32x16& a = (t == 0) ? acco0 : (t == 1) ? acco1 : acco2;
          #pragma unroll
          for (int reg = 0; reg < 16; ++reg){
            int r = (reg&3) + 8*(reg>>2) + 4*hi;
            long oi = (gbase + r)*267 + col;
            float val = a[reg] + bias;
            if (f32m) ((float*)out)[oi] = val;
            else      ((USHORT*)out)[oi] = f2b(val);
          }
        }
      }
    }
  }
}

// ---------------------------------------------------------------------------
// finalize: loss mean + perplexity from histogram
// ---------------------------------------------------------------------------
__global__ void vq_fin_kernel(const void* __restrict__ x,
                              const UINT* __restrict__ counts,
                              const float* __restrict__ loss_sum,
                              void* __restrict__ out)
{
  __shared__ float red[4];
  int f32m = detect_f32(x);
  int tid = threadIdx.x;
  float Hl = 0.f;
  for (int k = tid; k < 1024; k += 256){
    float p = (float)counts[k] * (1.f/65536.f);
    Hl -= p * logf(p + 1e-10f);
  }
  #pragma unroll
  for (int off = 32; off >= 1; off >>= 1) Hl += __shfl_xor(Hl, off, 64);
  if ((tid & 63) == 0) red[tid >> 6] = Hl;
  __syncthreads();
  if (tid == 0){
    float H = red[0] + red[1] + red[2] + red[3];
    float loss = *loss_sum * (1.f/4194304.f);   // /(B*L)
    float ppx  = expf(H);
    size_t base = (size_t)65536*267;
    if (f32m){
      ((float*)out)[base]     = loss;
      ((float*)out)[base + 1] = ppx;
    } else {
      ((USHORT*)out)[base]     = f2b(loss);
      ((USHORT*)out)[base + 1] = f2b(ppx);
    }
  }
}

// ---------------------------------------------------------------------------
extern "C" void kernel_launch(void* const* d_in, const int* in_sizes, int n_in,
                              void* d_out, int out_size, void* d_ws, size_t ws_size,
                              hipStream_t stream)
{
  const void* x    = d_in[0];
  const void* c    = d_in[1];
  const void* fc1w = d_in[2];
  const void* fc1b = d_in[3];
  const void* fc2w = d_in[4];
  const void* fc2b = d_in[5];
  const void* fc3w = d_in[6];
  const void* fc3b = d_in[7];
  const void* muw  = d_in[8];
  const void* mub  = d_in[9];
  const void* fc4w = d_in[10];
  const void* fc4b = d_in[11];
  const void* fc5w = d_in[12];
  const void* fc5b = d_in[13];
  const void* fc6w = d_in[14];
  const void* fc6b = d_in[15];
  const void* outw = d_in[16];
  const void* outb = d_in[17];
  const void* embed= d_in[18];

  char* ws = (char*)d_ws;
  UINT*   counts = (UINT*)  (ws + OFF_COUNTS);
  float*  lsum   = (float*) (ws + OFF_LOSS);
  float*  enorm  = (float*) (ws + OFF_ENORM);
  USHORT* W1p = (USHORT*)(ws + OFF_W1);
  USHORT* W2p = (USHORT*)(ws + OFF_W2);
  USHORT* W3p = (USHORT*)(ws + OFF_W3);
  USHORT* Wmup= (USHORT*)(ws + OFF_WMU);
  USHORT* Wep = (USHORT*)(ws + OFF_WE);
  USHORT* W4p = (USHORT*)(ws + OFF_W4);
  USHORT* W5p = (USHORT*)(ws + OFF_W5);
  USHORT* W6p = (USHORT*)(ws + OFF_W6);
  USHORT* Wop = (USHORT*)(ws + OFF_WO);

  // 2 elements/thread -> 272 blocks covers the largest table (544*256 elems)
  dim3 pgrid(272, 11, 1);
  vq_prep_kernel<<<pgrid, 256, 0, stream>>>(
      x, fc1w, fc2w, fc3w, muw, fc4w, fc5w, fc6w, outw, embed,
      W1p, W2p, W3p, Wmup, Wep, W4p, W5p, W6p, Wop, enorm, counts, lsum);

  vq_main_kernel<<<2048, 256, 0, stream>>>(
      x, c, fc1b, fc2b, fc3b, mub, fc4b, fc5b, fc6b, outb, embed,
      W1p, W2p, W3p, Wmup, Wep, enorm,
      W4p, W5p, W6p, Wop, counts, lsum, d_out);

  vq_fin_kernel<<<1, 256, 0, stream>>>(x, counts, lsum, d_out);
}